// Round 1
// baseline (820.086 us; speedup 1.0000x reference)
//
#include <hip/hip_runtime.h>

#define N_NODES 50000
#define N_EDGES 800000
#define HDIM 128
#define ODIM 64
#define NLAYER 3
#define NGRAPH 512
#define BN_EPS 1e-5f
#define PITCH 136   // 128 + 8 bf16 pad -> 16B pad, 2-way max bank aliasing (free)

typedef __attribute__((ext_vector_type(8))) short short8;
typedef __attribute__((ext_vector_type(4))) float floatx4;

static __device__ __forceinline__ unsigned short f2bf(float f) {
    union { float f; unsigned int u; } v; v.f = f;
    unsigned int r = v.u + 0x7FFFu + ((v.u >> 16) & 1u);
    return (unsigned short)(r >> 16);
}
static __device__ __forceinline__ float bf2f(unsigned short s) {
    union { unsigned int u; float f; } v; v.u = ((unsigned int)s) << 16;
    return v.f;
}

// ---------------- CSR build ----------------

__global__ __launch_bounds__(256) void k_hist(const int* __restrict__ dst,
                                              int* __restrict__ deg) {
    int e = blockIdx.x * 256 + threadIdx.x;
    if (e < N_EDGES) atomicAdd(&deg[dst[e]], 1);
}

__global__ __launch_bounds__(1024) void k_scan(const int* __restrict__ deg,
                                               int* __restrict__ rowptr,
                                               int* __restrict__ cursor) {
    __shared__ int sums[1024];
    const int CH = 49;  // ceil(50000/1024)
    int tid = threadIdx.x;
    int base = tid * CH;
    int s = 0;
    for (int i = 0; i < CH; ++i) {
        int idx = base + i;
        if (idx < N_NODES) s += deg[idx];
    }
    sums[tid] = s;
    __syncthreads();
    // Hillis-Steele inclusive scan
    for (int off = 1; off < 1024; off <<= 1) {
        int v = (tid >= off) ? sums[tid - off] : 0;
        __syncthreads();
        sums[tid] += v;
        __syncthreads();
    }
    int run = sums[tid] - s;  // exclusive prefix
    for (int i = 0; i < CH; ++i) {
        int idx = base + i;
        if (idx < N_NODES) {
            rowptr[idx] = run;
            cursor[idx] = run;
            run += deg[idx];
        }
    }
    if (tid == 1023) rowptr[N_NODES] = N_EDGES;
}

__global__ __launch_bounds__(256) void k_scatter(const int* __restrict__ src,
                                                 const int* __restrict__ dst,
                                                 int* __restrict__ cursor,
                                                 int* __restrict__ colidx) {
    int e = blockIdx.x * 256 + threadIdx.x;
    if (e < N_EDGES) {
        int pos = atomicAdd(&cursor[dst[e]], 1);
        colidx[pos] = src[e];
    }
}

// ---------------- f32 -> bf16 convert ----------------

__global__ __launch_bounds__(256) void k_cvt(const float* __restrict__ x,
                                             unsigned short* __restrict__ xb) {
    int i = blockIdx.x * 256 + threadIdx.x;  // one float4 each
    if (i < N_NODES * HDIM / 4) {
        float4 v = ((const float4*)x)[i];
        ushort4 o = make_ushort4(f2bf(v.x), f2bf(v.y), f2bf(v.z), f2bf(v.w));
        ((ushort4*)xb)[i] = o;
    }
}

// ---------------- Layer K1: aggregate + GEMM1 + bias + BN stats ----------------
// block: 256 threads, 64 rows. x in bf16, h out bf16, stats f32 (sum, sumsq).

__global__ __launch_bounds__(256) void k_layer1(
    const unsigned short* __restrict__ xin,
    const int* __restrict__ rowptr,
    const int* __restrict__ colidx,
    const float* __restrict__ W1,   // [128][128] (k-major)
    const float* __restrict__ b1,   // [128]
    unsigned short* __restrict__ hout,
    float* __restrict__ stats)      // [2][128]
{
    __shared__ unsigned short yb[64 * PITCH];
    __shared__ unsigned short wt[HDIM * PITCH];   // transposed: wt[n][k]
    __shared__ float s_sum[HDIM], s_sq[HDIM], s_b[HDIM];

    int tid = threadIdx.x;
    int r0 = blockIdx.x * 64;

    // W1 -> LDS transposed bf16
    for (int idx = tid; idx < HDIM * HDIM; idx += 256) {
        int k = idx >> 7, n = idx & 127;
        wt[n * PITCH + k] = f2bf(W1[idx]);
    }
    if (tid < HDIM) { s_sum[tid] = 0.f; s_sq[tid] = 0.f; s_b[tid] = b1[tid]; }

    // aggregation: 32 threads/row (one float-quad each), 8 rows/pass, 8 passes
    int cg4 = (tid & 31) * 4;
    int rsub = tid >> 5;
    for (int p = 0; p < 8; ++p) {
        int rloc = p * 8 + rsub;
        int row = r0 + rloc;
        float a0 = 0.f, a1 = 0.f, a2 = 0.f, a3 = 0.f;
        if (row < N_NODES) {
            ushort4 v = *(const ushort4*)(xin + (size_t)row * HDIM + cg4);
            a0 = bf2f(v.x); a1 = bf2f(v.y); a2 = bf2f(v.z); a3 = bf2f(v.w);
            int beg = rowptr[row], end = rowptr[row + 1];
            int e = beg;
            for (; e + 2 <= end; e += 2) {
                int j0 = colidx[e], j1 = colidx[e + 1];
                ushort4 v0 = *(const ushort4*)(xin + (size_t)j0 * HDIM + cg4);
                ushort4 v1 = *(const ushort4*)(xin + (size_t)j1 * HDIM + cg4);
                a0 += bf2f(v0.x) + bf2f(v1.x);
                a1 += bf2f(v0.y) + bf2f(v1.y);
                a2 += bf2f(v0.z) + bf2f(v1.z);
                a3 += bf2f(v0.w) + bf2f(v1.w);
            }
            if (e < end) {
                int j0 = colidx[e];
                ushort4 v0 = *(const ushort4*)(xin + (size_t)j0 * HDIM + cg4);
                a0 += bf2f(v0.x); a1 += bf2f(v0.y); a2 += bf2f(v0.z); a3 += bf2f(v0.w);
            }
        }
        ushort4 o = make_ushort4(f2bf(a0), f2bf(a1), f2bf(a2), f2bf(a3));
        *(ushort4*)&yb[rloc * PITCH + cg4] = o;
    }
    __syncthreads();

    // MFMA: wave w computes rows [16w,16w+16) x all 128 cols
    int wv = tid >> 6;
    int lane = tid & 63;
    int m = lane & 15;
    int quad = lane >> 4;

    short8 afrag[4];
#pragma unroll
    for (int kk = 0; kk < 4; ++kk)
        afrag[kk] = *(const short8*)&yb[(wv * 16 + m) * PITCH + kk * 32 + quad * 8];

    floatx4 acc[8];
#pragma unroll
    for (int nt = 0; nt < 8; ++nt) {
        floatx4 c = {0.f, 0.f, 0.f, 0.f};
#pragma unroll
        for (int kk = 0; kk < 4; ++kk) {
            short8 bfrag = *(const short8*)&wt[(nt * 16 + m) * PITCH + kk * 32 + quad * 8];
            c = __builtin_amdgcn_mfma_f32_16x16x32_bf16(afrag[kk], bfrag, c, 0, 0, 0);
        }
        acc[nt] = c;
    }

    // epilogue: +b1, write bf16 h, accumulate BN partial stats
    int rbase = r0 + wv * 16 + quad * 4;
#pragma unroll
    for (int nt = 0; nt < 8; ++nt) {
        int n = nt * 16 + m;
        float bias = s_b[n];
        float ssum = 0.f, ssq = 0.f;
#pragma unroll
        for (int r = 0; r < 4; ++r) {
            int row = rbase + r;
            if (row < N_NODES) {
                float val = acc[nt][r] + bias;
                hout[(size_t)row * HDIM + n] = f2bf(val);
                ssum += val;
                ssq += val * val;
            }
        }
        atomicAdd(&s_sum[n], ssum);
        atomicAdd(&s_sq[n], ssq);
    }
    __syncthreads();
    if (tid < HDIM) {
        atomicAdd(&stats[tid], s_sum[tid]);
        atomicAdd(&stats[HDIM + tid], s_sq[tid]);
    }
}

// ---------------- Layer K2: BN + ReLU + GEMM2 + bias + ReLU ----------------

__global__ __launch_bounds__(256) void k_layer2(
    const unsigned short* __restrict__ hin,
    const float* __restrict__ stats,
    const float* __restrict__ gamma,
    const float* __restrict__ beta,
    const float* __restrict__ W2,
    const float* __restrict__ b2,
    unsigned short* __restrict__ xout)
{
    __shared__ unsigned short ub[64 * PITCH];
    __shared__ unsigned short wt[HDIM * PITCH];
    __shared__ float s_scale[HDIM], s_shift[HDIM], s_b[HDIM];

    int tid = threadIdx.x;
    int r0 = blockIdx.x * 64;

    for (int idx = tid; idx < HDIM * HDIM; idx += 256) {
        int k = idx >> 7, n = idx & 127;
        wt[n * PITCH + k] = f2bf(W2[idx]);
    }
    if (tid < HDIM) {
        float mu = stats[tid] * (1.f / N_NODES);
        float var = stats[HDIM + tid] * (1.f / N_NODES) - mu * mu;
        float sc = gamma[tid] * rsqrtf(var + BN_EPS);
        s_scale[tid] = sc;
        s_shift[tid] = beta[tid] - mu * sc;
        s_b[tid] = b2[tid];
    }
    __syncthreads();

    int cg4 = (tid & 31) * 4;
    int rsub = tid >> 5;
    float sc0 = s_scale[cg4 + 0], sh0 = s_shift[cg4 + 0];
    float sc1 = s_scale[cg4 + 1], sh1 = s_shift[cg4 + 1];
    float sc2 = s_scale[cg4 + 2], sh2 = s_shift[cg4 + 2];
    float sc3 = s_scale[cg4 + 3], sh3 = s_shift[cg4 + 3];
    for (int p = 0; p < 8; ++p) {
        int rloc = p * 8 + rsub;
        int row = r0 + rloc;
        ushort4 o;
        if (row < N_NODES) {
            ushort4 v = *(const ushort4*)(hin + (size_t)row * HDIM + cg4);
            float f0 = fmaxf(bf2f(v.x) * sc0 + sh0, 0.f);
            float f1 = fmaxf(bf2f(v.y) * sc1 + sh1, 0.f);
            float f2 = fmaxf(bf2f(v.z) * sc2 + sh2, 0.f);
            float f3 = fmaxf(bf2f(v.w) * sc3 + sh3, 0.f);
            o = make_ushort4(f2bf(f0), f2bf(f1), f2bf(f2), f2bf(f3));
        } else {
            o = make_ushort4(0, 0, 0, 0);
        }
        *(ushort4*)&ub[rloc * PITCH + cg4] = o;
    }
    __syncthreads();

    int wv = tid >> 6;
    int lane = tid & 63;
    int m = lane & 15;
    int quad = lane >> 4;

    short8 afrag[4];
#pragma unroll
    for (int kk = 0; kk < 4; ++kk)
        afrag[kk] = *(const short8*)&ub[(wv * 16 + m) * PITCH + kk * 32 + quad * 8];

    floatx4 acc[8];
#pragma unroll
    for (int nt = 0; nt < 8; ++nt) {
        floatx4 c = {0.f, 0.f, 0.f, 0.f};
#pragma unroll
        for (int kk = 0; kk < 4; ++kk) {
            short8 bfrag = *(const short8*)&wt[(nt * 16 + m) * PITCH + kk * 32 + quad * 8];
            c = __builtin_amdgcn_mfma_f32_16x16x32_bf16(afrag[kk], bfrag, c, 0, 0, 0);
        }
        acc[nt] = c;
    }

    int rbase = r0 + wv * 16 + quad * 4;
#pragma unroll
    for (int nt = 0; nt < 8; ++nt) {
        int n = nt * 16 + m;
        float bias = s_b[n];
#pragma unroll
        for (int r = 0; r < 4; ++r) {
            int row = rbase + r;
            if (row < N_NODES) {
                float val = fmaxf(acc[nt][r] + bias, 0.f);
                xout[(size_t)row * HDIM + n] = f2bf(val);
            }
        }
    }
}

// ---------------- pool + head ----------------
// one block per graph; batch is sorted so rows are contiguous

__global__ __launch_bounds__(128) void k_poolhead(
    const unsigned short* __restrict__ xf,
    const int* __restrict__ batch,
    const float* __restrict__ hW1, const float* __restrict__ hb1,
    const float* __restrict__ hW2, const float* __restrict__ hb2,
    float* __restrict__ out)
{
    __shared__ float grow[HDIM], th[HDIM];
    int g = blockIdx.x;
    int c = threadIdx.x;

    // lower_bound(batch, g) and lower_bound(batch, g+1)
    int lo = 0, hi = N_NODES;
    while (lo < hi) { int mid = (lo + hi) >> 1; if (batch[mid] < g) lo = mid + 1; else hi = mid; }
    int start = lo;
    int lo2 = start, hi2 = N_NODES;
    while (lo2 < hi2) { int mid = (lo2 + hi2) >> 1; if (batch[mid] < g + 1) lo2 = mid + 1; else hi2 = mid; }
    int end = lo2;

    float s = 0.f;
    for (int r = start; r < end; ++r) s += bf2f(xf[(size_t)r * HDIM + c]);
    grow[c] = s;
    __syncthreads();

    float acc = hb1[c];
    for (int k = 0; k < HDIM; ++k) acc += grow[k] * hW1[k * HDIM + c];
    th[c] = fmaxf(acc, 0.f);
    __syncthreads();

    if (c < ODIM) {
        float o = hb2[c];
        for (int k = 0; k < HDIM; ++k) o += th[k] * hW2[k * ODIM + c];
        out[(size_t)g * ODIM + c] = o;
    }
}

// ---------------- launch ----------------

extern "C" void kernel_launch(void* const* d_in, const int* in_sizes, int n_in,
                              void* d_out, int out_size, void* d_ws, size_t ws_size,
                              hipStream_t stream) {
    const float* x        = (const float*)d_in[0];
    const float* conv_W1  = (const float*)d_in[1];
    const float* conv_b1  = (const float*)d_in[2];
    const float* conv_g   = (const float*)d_in[3];
    const float* conv_be  = (const float*)d_in[4];
    const float* conv_W2  = (const float*)d_in[5];
    const float* conv_b2  = (const float*)d_in[6];
    const float* head_W1  = (const float*)d_in[7];
    const float* head_b1  = (const float*)d_in[8];
    const float* head_W2  = (const float*)d_in[9];
    const float* head_b2  = (const float*)d_in[10];
    const int*   edges    = (const int*)d_in[11];   // [0..E)=src, [E..2E)=dst
    const int*   batch    = (const int*)d_in[12];

    char* ws = (char*)d_ws;
    int*            deg    = (int*)(ws + 0);                 // 200000 B
    float*          stats  = (float*)(ws + 200000);          // 3*2*128*4 = 3072 B
    int*            rowptr = (int*)(ws + 203072);            // 200004 B
    int*            cursor = (int*)(ws + 403088);            // 200000 B
    int*            colidx = (int*)(ws + 603088);            // 3.2 MB
    unsigned short* xa     = (unsigned short*)(ws + 3803088);   // 12.8 MB
    unsigned short* xb     = (unsigned short*)(ws + 16603088);  // 12.8 MB
    unsigned short* hbuf   = (unsigned short*)(ws + 29403088);  // 12.8 MB
    (void)in_sizes; (void)n_in; (void)out_size; (void)ws_size;

    // zero deg + stats (ws is poisoned 0xAA before every call)
    hipMemsetAsync(ws, 0, 203072, stream);

    // CSR by dst
    k_hist<<<(N_EDGES + 255) / 256, 256, 0, stream>>>(edges + N_EDGES, deg);
    k_scan<<<1, 1024, 0, stream>>>(deg, rowptr, cursor);
    k_scatter<<<(N_EDGES + 255) / 256, 256, 0, stream>>>(edges, edges + N_EDGES, cursor, colidx);

    // x -> bf16
    k_cvt<<<(N_NODES * HDIM / 4 + 255) / 256, 256, 0, stream>>>(x, xa);

    const int nblk = (N_NODES + 63) / 64;  // 782
    unsigned short* cur = xa;
    unsigned short* nxt = xb;
    for (int l = 0; l < NLAYER; ++l) {
        k_layer1<<<nblk, 256, 0, stream>>>(cur, rowptr, colidx,
                                           conv_W1 + l * HDIM * HDIM,
                                           conv_b1 + l * HDIM,
                                           hbuf, stats + l * 2 * HDIM);
        k_layer2<<<nblk, 256, 0, stream>>>(hbuf, stats + l * 2 * HDIM,
                                           conv_g + l * HDIM, conv_be + l * HDIM,
                                           conv_W2 + l * HDIM * HDIM,
                                           conv_b2 + l * HDIM,
                                           nxt);
        unsigned short* t = cur; cur = nxt; nxt = t;
    }

    k_poolhead<<<NGRAPH, 128, 0, stream>>>(cur, batch, head_W1, head_b1,
                                           head_W2, head_b2, (float*)d_out);
}

// Round 2
// 651.437 us; speedup vs baseline: 1.2589x; 1.2589x over previous
//
#include <hip/hip_runtime.h>

#define N_NODES 50000
#define N_EDGES 800000
#define HDIM 128
#define ODIM 64
#define NLAYER 3
#define NGRAPH 512
#define BN_EPS 1e-5f

typedef __attribute__((ext_vector_type(8))) short short8;
typedef __attribute__((ext_vector_type(4))) float floatx4;

static __device__ __forceinline__ unsigned short f2bf(float f) {
    union { float f; unsigned int u; } v; v.f = f;
    unsigned int r = v.u + 0x7FFFu + ((v.u >> 16) & 1u);
    return (unsigned short)(r >> 16);
}
static __device__ __forceinline__ float bf2f(unsigned short s) {
    union { unsigned int u; float f; } v; v.u = ((unsigned int)s) << 16;
    return v.f;
}

// ---------------- CSR build ----------------

__global__ __launch_bounds__(256) void k_hist(const int* __restrict__ dst,
                                              int* __restrict__ deg) {
    int e = blockIdx.x * 256 + threadIdx.x;
    if (e < N_EDGES) atomicAdd(&deg[dst[e]], 1);
}

__global__ __launch_bounds__(1024) void k_scan(const int* __restrict__ deg,
                                               int* __restrict__ rowptr,
                                               int* __restrict__ cursor) {
    __shared__ int sums[1024];
    const int CH = 49;  // ceil(50000/1024)
    int tid = threadIdx.x;
    int base = tid * CH;
    int s = 0;
    for (int i = 0; i < CH; ++i) {
        int idx = base + i;
        if (idx < N_NODES) s += deg[idx];
    }
    sums[tid] = s;
    __syncthreads();
    for (int off = 1; off < 1024; off <<= 1) {
        int v = (tid >= off) ? sums[tid - off] : 0;
        __syncthreads();
        sums[tid] += v;
        __syncthreads();
    }
    int run = sums[tid] - s;  // exclusive prefix
    for (int i = 0; i < CH; ++i) {
        int idx = base + i;
        if (idx < N_NODES) {
            rowptr[idx] = run;
            cursor[idx] = run;
            run += deg[idx];
        }
    }
    if (tid == 1023) rowptr[N_NODES] = N_EDGES;
}

__global__ __launch_bounds__(256) void k_scatter(const int* __restrict__ src,
                                                 const int* __restrict__ dst,
                                                 int* __restrict__ cursor,
                                                 int* __restrict__ colidx) {
    int e = blockIdx.x * 256 + threadIdx.x;
    if (e < N_EDGES) {
        int pos = atomicAdd(&cursor[dst[e]], 1);
        colidx[pos] = src[e];
    }
}

// ---------------- converts ----------------

__global__ __launch_bounds__(256) void k_cvt(const float* __restrict__ x,
                                             unsigned short* __restrict__ xb) {
    int i = blockIdx.x * 256 + threadIdx.x;
    if (i < N_NODES * HDIM / 4) {
        float4 v = ((const float4*)x)[i];
        ushort4 o = make_ushort4(f2bf(v.x), f2bf(v.y), f2bf(v.z), f2bf(v.w));
        ((ushort4*)xb)[i] = o;
    }
}

// 6 weight matrices [k][n] f32 -> transposed [n][k] bf16; mat 2l=W1[l], 2l+1=W2[l]
__global__ __launch_bounds__(256) void k_cvtW(const float* __restrict__ W1,
                                              const float* __restrict__ W2,
                                              unsigned short* __restrict__ wtb) {
    int idx = blockIdx.x * 256 + threadIdx.x;
    if (idx < 6 * HDIM * HDIM) {
        int mat = idx >> 14;
        int rem = idx & 16383;
        int k = rem >> 7, n = rem & 127;
        int l = mat >> 1;
        const float* W = (mat & 1) ? (W2 + l * HDIM * HDIM) : (W1 + l * HDIM * HDIM);
        wtb[mat * HDIM * HDIM + n * HDIM + k] = f2bf(W[k * HDIM + n]);
    }
}

// ---------------- gather: y[n] = x[n] + sum_{j in N(n)} x[j] ----------------
// 16 lanes per node, 16 B (8 bf16 cols) per lane. LDS-free, high occupancy.

__global__ __launch_bounds__(256) void k_gather(
    const unsigned short* __restrict__ x,
    const int* __restrict__ rowptr,
    const int* __restrict__ colidx,
    unsigned short* __restrict__ y)
{
    int t = blockIdx.x * 256 + threadIdx.x;
    int node = t >> 4;
    int seg = (t & 15) * 8;          // col offset (8 bf16 = 16 B)
    if (node >= N_NODES) return;

    float acc[8];
    {
        short8 v = *(const short8*)(x + (size_t)node * HDIM + seg);
#pragma unroll
        for (int j = 0; j < 8; ++j) acc[j] = bf2f((unsigned short)v[j]);
    }
    int e = rowptr[node];
    int end = rowptr[node + 1];
    for (; e + 4 <= end; e += 4) {
        int j0 = colidx[e], j1 = colidx[e + 1], j2 = colidx[e + 2], j3 = colidx[e + 3];
        short8 v0 = *(const short8*)(x + (size_t)j0 * HDIM + seg);
        short8 v1 = *(const short8*)(x + (size_t)j1 * HDIM + seg);
        short8 v2 = *(const short8*)(x + (size_t)j2 * HDIM + seg);
        short8 v3 = *(const short8*)(x + (size_t)j3 * HDIM + seg);
#pragma unroll
        for (int j = 0; j < 8; ++j)
            acc[j] += (bf2f((unsigned short)v0[j]) + bf2f((unsigned short)v1[j])) +
                      (bf2f((unsigned short)v2[j]) + bf2f((unsigned short)v3[j]));
    }
    for (; e < end; ++e) {
        int j0 = colidx[e];
        short8 v0 = *(const short8*)(x + (size_t)j0 * HDIM + seg);
#pragma unroll
        for (int j = 0; j < 8; ++j) acc[j] += bf2f((unsigned short)v0[j]);
    }
    short8 o;
#pragma unroll
    for (int j = 0; j < 8; ++j) o[j] = (short)f2bf(acc[j]);
    *(short8*)(y + (size_t)node * HDIM + seg) = o;
}

// ---------------- mlp1: h = y @ W1 + b1, partial BN stats ----------------
// LDS-free MFMA: A from y (global), B from wtb (global, L2-hot). 64 rows/block.

__global__ __launch_bounds__(256) void k_mlp1(
    const unsigned short* __restrict__ y,
    const unsigned short* __restrict__ wt,   // [n][k] bf16
    const float* __restrict__ b1,
    unsigned short* __restrict__ hout,
    float* __restrict__ stats)               // [2][128]
{
    __shared__ float s_sum[HDIM], s_sq[HDIM];
    int tid = threadIdx.x;
    if (tid < HDIM) { s_sum[tid] = 0.f; s_sq[tid] = 0.f; }
    __syncthreads();

    int wv = tid >> 6, lane = tid & 63;
    int m = lane & 15, quad = lane >> 4;
    int row0 = blockIdx.x * 64 + wv * 16;
    int arow = row0 + m;

    short8 a[4];
    if (arow < N_NODES) {
#pragma unroll
        for (int kk = 0; kk < 4; ++kk)
            a[kk] = *(const short8*)(y + (size_t)arow * HDIM + kk * 32 + quad * 8);
    } else {
#pragma unroll
        for (int kk = 0; kk < 4; ++kk) a[kk] = (short8)0;
    }

    floatx4 acc[8];
#pragma unroll
    for (int nt = 0; nt < 8; ++nt) {
        floatx4 c = {0.f, 0.f, 0.f, 0.f};
#pragma unroll
        for (int kk = 0; kk < 4; ++kk) {
            short8 b = *(const short8*)(wt + (nt * 16 + m) * HDIM + kk * 32 + quad * 8);
            c = __builtin_amdgcn_mfma_f32_16x16x32_bf16(a[kk], b, c, 0, 0, 0);
        }
        acc[nt] = c;
    }

    int rbase = row0 + quad * 4;
#pragma unroll
    for (int nt = 0; nt < 8; ++nt) {
        int n = nt * 16 + m;
        float bias = b1[n];
        float ssum = 0.f, ssq = 0.f;
#pragma unroll
        for (int r = 0; r < 4; ++r) {
            int row = rbase + r;
            if (row < N_NODES) {
                float val = acc[nt][r] + bias;
                hout[(size_t)row * HDIM + n] = f2bf(val);
                ssum += val;
                ssq += val * val;
            }
        }
        atomicAdd(&s_sum[n], ssum);
        atomicAdd(&s_sq[n], ssq);
    }
    __syncthreads();
    if (tid < HDIM) {
        atomicAdd(&stats[tid], s_sum[tid]);
        atomicAdd(&stats[HDIM + tid], s_sq[tid]);
    }
}

// ---------------- mlp2: x' = relu(BN(h) relu'd @ W2 + b2) ----------------

__global__ __launch_bounds__(256) void k_mlp2(
    const unsigned short* __restrict__ hin,
    const float* __restrict__ stats,
    const float* __restrict__ gamma,
    const float* __restrict__ beta,
    const unsigned short* __restrict__ wt,   // [n][k] bf16
    const float* __restrict__ b2,
    unsigned short* __restrict__ xout)
{
    __shared__ float s_scale[HDIM], s_shift[HDIM];
    int tid = threadIdx.x;
    if (tid < HDIM) {
        float mu = stats[tid] * (1.f / N_NODES);
        float var = stats[HDIM + tid] * (1.f / N_NODES) - mu * mu;
        float sc = gamma[tid] * rsqrtf(var + BN_EPS);
        s_scale[tid] = sc;
        s_shift[tid] = beta[tid] - mu * sc;
    }
    __syncthreads();

    int wv = tid >> 6, lane = tid & 63;
    int m = lane & 15, quad = lane >> 4;
    int row0 = blockIdx.x * 64 + wv * 16;
    int arow = row0 + m;

    short8 a[4];
    if (arow < N_NODES) {
#pragma unroll
        for (int kk = 0; kk < 4; ++kk) {
            short8 v = *(const short8*)(hin + (size_t)arow * HDIM + kk * 32 + quad * 8);
            int c0 = kk * 32 + quad * 8;
            short8 af;
#pragma unroll
            for (int j = 0; j < 8; ++j) {
                float f = fmaxf(bf2f((unsigned short)v[j]) * s_scale[c0 + j] + s_shift[c0 + j], 0.f);
                af[j] = (short)f2bf(f);
            }
            a[kk] = af;
        }
    } else {
#pragma unroll
        for (int kk = 0; kk < 4; ++kk) a[kk] = (short8)0;
    }

    floatx4 acc[8];
#pragma unroll
    for (int nt = 0; nt < 8; ++nt) {
        floatx4 c = {0.f, 0.f, 0.f, 0.f};
#pragma unroll
        for (int kk = 0; kk < 4; ++kk) {
            short8 b = *(const short8*)(wt + (nt * 16 + m) * HDIM + kk * 32 + quad * 8);
            c = __builtin_amdgcn_mfma_f32_16x16x32_bf16(a[kk], b, c, 0, 0, 0);
        }
        acc[nt] = c;
    }

    int rbase = row0 + quad * 4;
#pragma unroll
    for (int nt = 0; nt < 8; ++nt) {
        int n = nt * 16 + m;
        float bias = b2[n];
#pragma unroll
        for (int r = 0; r < 4; ++r) {
            int row = rbase + r;
            if (row < N_NODES) {
                float val = fmaxf(acc[nt][r] + bias, 0.f);
                xout[(size_t)row * HDIM + n] = f2bf(val);
            }
        }
    }
}

// ---------------- pool + head ----------------

__global__ __launch_bounds__(128) void k_poolhead(
    const unsigned short* __restrict__ xf,
    const int* __restrict__ batch,
    const float* __restrict__ hW1, const float* __restrict__ hb1,
    const float* __restrict__ hW2, const float* __restrict__ hb2,
    float* __restrict__ out)
{
    __shared__ float grow[HDIM], th[HDIM];
    int g = blockIdx.x;
    int c = threadIdx.x;

    int lo = 0, hi = N_NODES;
    while (lo < hi) { int mid = (lo + hi) >> 1; if (batch[mid] < g) lo = mid + 1; else hi = mid; }
    int start = lo;
    int lo2 = start, hi2 = N_NODES;
    while (lo2 < hi2) { int mid = (lo2 + hi2) >> 1; if (batch[mid] < g + 1) lo2 = mid + 1; else hi2 = mid; }
    int end = lo2;

    float s = 0.f;
    for (int r = start; r < end; ++r) s += bf2f(xf[(size_t)r * HDIM + c]);
    grow[c] = s;
    __syncthreads();

    float acc = hb1[c];
    for (int k = 0; k < HDIM; ++k) acc += grow[k] * hW1[k * HDIM + c];
    th[c] = fmaxf(acc, 0.f);
    __syncthreads();

    if (c < ODIM) {
        float o = hb2[c];
        for (int k = 0; k < HDIM; ++k) o += th[k] * hW2[k * ODIM + c];
        out[(size_t)g * ODIM + c] = o;
    }
}

// ---------------- launch ----------------

extern "C" void kernel_launch(void* const* d_in, const int* in_sizes, int n_in,
                              void* d_out, int out_size, void* d_ws, size_t ws_size,
                              hipStream_t stream) {
    const float* x        = (const float*)d_in[0];
    const float* conv_W1  = (const float*)d_in[1];
    const float* conv_b1  = (const float*)d_in[2];
    const float* conv_g   = (const float*)d_in[3];
    const float* conv_be  = (const float*)d_in[4];
    const float* conv_W2  = (const float*)d_in[5];
    const float* conv_b2  = (const float*)d_in[6];
    const float* head_W1  = (const float*)d_in[7];
    const float* head_b1  = (const float*)d_in[8];
    const float* head_W2  = (const float*)d_in[9];
    const float* head_b2  = (const float*)d_in[10];
    const int*   edges    = (const int*)d_in[11];   // [0..E)=src, [E..2E)=dst
    const int*   batch    = (const int*)d_in[12];

    char* ws = (char*)d_ws;
    int*            deg    = (int*)(ws + 0);                  // 200000 B
    float*          stats  = (float*)(ws + 200000);           // 3072 B
    int*            rowptr = (int*)(ws + 203072);             // 200004 B
    int*            cursor = (int*)(ws + 403088);             // 200000 B
    int*            colidx = (int*)(ws + 603088);             // 3.2 MB
    unsigned short* wtb    = (unsigned short*)(ws + 3803088); // 196608 B
    unsigned short* xa     = (unsigned short*)(ws + 4000000); // 12.8 MB
    unsigned short* xb     = (unsigned short*)(ws + 16800000);// 12.8 MB
    unsigned short* hbuf   = (unsigned short*)(ws + 29600000);// 12.8 MB
    (void)in_sizes; (void)n_in; (void)out_size; (void)ws_size;

    hipMemsetAsync(ws, 0, 203072, stream);  // deg + stats

    k_hist<<<(N_EDGES + 255) / 256, 256, 0, stream>>>(edges + N_EDGES, deg);
    k_scan<<<1, 1024, 0, stream>>>(deg, rowptr, cursor);
    k_scatter<<<(N_EDGES + 255) / 256, 256, 0, stream>>>(edges, edges + N_EDGES, cursor, colidx);

    k_cvt<<<(N_NODES * HDIM / 4 + 255) / 256, 256, 0, stream>>>(x, xa);
    k_cvtW<<<(6 * HDIM * HDIM + 255) / 256, 256, 0, stream>>>(conv_W1, conv_W2, wtb);

    const int nblk = (N_NODES + 63) / 64;         // 782
    const int gblk = (N_NODES * 16 + 255) / 256;  // 3125
    unsigned short* cur = xa;
    unsigned short* nxt = xb;
    for (int l = 0; l < NLAYER; ++l) {
        // y goes into nxt (consumed by mlp1 before mlp2 overwrites nxt)
        k_gather<<<gblk, 256, 0, stream>>>(cur, rowptr, colidx, nxt);
        k_mlp1<<<nblk, 256, 0, stream>>>(nxt, wtb + (2 * l) * HDIM * HDIM,
                                         conv_b1 + l * HDIM, hbuf,
                                         stats + l * 2 * HDIM);
        k_mlp2<<<nblk, 256, 0, stream>>>(hbuf, stats + l * 2 * HDIM,
                                         conv_g + l * HDIM, conv_be + l * HDIM,
                                         wtb + (2 * l + 1) * HDIM * HDIM,
                                         conv_b2 + l * HDIM, nxt);
        unsigned short* t = cur; cur = nxt; nxt = t;
    }

    k_poolhead<<<NGRAPH, 128, 0, stream>>>(cur, batch, head_W1, head_b1,
                                           head_W2, head_b2, (float*)d_out);
}

// Round 3
// 540.711 us; speedup vs baseline: 1.5167x; 1.2048x over previous
//
#include <hip/hip_runtime.h>

#define N_NODES 50000
#define N_EDGES 800000
#define HDIM 128
#define ODIM 64
#define NLAYER 3
#define NGRAPH 512
#define BN_EPS 1e-5f

typedef __attribute__((ext_vector_type(8))) short short8;
typedef __attribute__((ext_vector_type(4))) float floatx4;

static __device__ __forceinline__ unsigned short f2bf(float f) {
    union { float f; unsigned int u; } v; v.f = f;
    unsigned int r = v.u + 0x7FFFu + ((v.u >> 16) & 1u);
    return (unsigned short)(r >> 16);
}
static __device__ __forceinline__ float bf2f(unsigned short s) {
    union { unsigned int u; float f; } v; v.u = ((unsigned int)s) << 16;
    return v.f;
}

// ---------------- CSR build (unordered segment allocation) ----------------

__global__ __launch_bounds__(256) void k_hist(const int* __restrict__ dst,
                                              int* __restrict__ deg) {
    int e = blockIdx.x * 256 + threadIdx.x;
    if (e < N_EDGES) atomicAdd(&deg[dst[e]], 1);
}

// Allocate per-node colidx segments via wave-aggregated atomics.
// Segments are disjoint and pack [0,E) but in arbitrary node order — gather
// only needs [beg, beg+deg) so ordering is irrelevant.
__global__ __launch_bounds__(256) void k_alloc(const int* __restrict__ deg,
                                               int* __restrict__ rowbeg,
                                               int* __restrict__ cursor,
                                               int* __restrict__ counter) {
    int n = blockIdx.x * 256 + threadIdx.x;
    int d = (n < N_NODES) ? deg[n] : 0;
    int lane = threadIdx.x & 63;
    int incl = d;
#pragma unroll
    for (int off = 1; off < 64; off <<= 1) {
        int v = __shfl_up(incl, off, 64);
        if (lane >= off) incl += v;
    }
    int waveTotal = __shfl(incl, 63, 64);
    int base = 0;
    if (lane == 0) base = atomicAdd(counter, waveTotal);
    base = __shfl(base, 0, 64);
    if (n < N_NODES) {
        int s = base + incl - d;
        rowbeg[n] = s;
        cursor[n] = s;
    }
}

__global__ __launch_bounds__(256) void k_scatter(const int* __restrict__ src,
                                                 const int* __restrict__ dst,
                                                 int* __restrict__ cursor,
                                                 int* __restrict__ colidx) {
    int e = blockIdx.x * 256 + threadIdx.x;
    if (e < N_EDGES) {
        int pos = atomicAdd(&cursor[dst[e]], 1);
        colidx[pos] = src[e];
    }
}

// ---------------- converts ----------------

__global__ __launch_bounds__(256) void k_cvt(const float* __restrict__ x,
                                             unsigned short* __restrict__ xb) {
    int i = blockIdx.x * 256 + threadIdx.x;
    if (i < N_NODES * HDIM / 4) {
        float4 v = ((const float4*)x)[i];
        ushort4 o = make_ushort4(f2bf(v.x), f2bf(v.y), f2bf(v.z), f2bf(v.w));
        ((ushort4*)xb)[i] = o;
    }
}

// 6 weight matrices [k][n] f32 -> transposed [n][k] bf16; mat 2l=W1[l], 2l+1=W2[l]
__global__ __launch_bounds__(256) void k_cvtW(const float* __restrict__ W1,
                                              const float* __restrict__ W2,
                                              unsigned short* __restrict__ wtb) {
    int idx = blockIdx.x * 256 + threadIdx.x;
    if (idx < 6 * HDIM * HDIM) {
        int mat = idx >> 14;
        int rem = idx & 16383;
        int k = rem >> 7, n = rem & 127;
        int l = mat >> 1;
        const float* W = (mat & 1) ? (W2 + l * HDIM * HDIM) : (W1 + l * HDIM * HDIM);
        wtb[mat * HDIM * HDIM + n * HDIM + k] = f2bf(W[k * HDIM + n]);
    }
}

// ---------------- gather: y[n] = x[n] + sum_{j in N(n)} x[j] ----------------
// 16 lanes per node, 16 B (8 bf16 cols) per lane. LDS-free, high occupancy.

__global__ __launch_bounds__(256) void k_gather(
    const unsigned short* __restrict__ x,
    const int* __restrict__ rowbeg,
    const int* __restrict__ deg,
    const int* __restrict__ colidx,
    unsigned short* __restrict__ y)
{
    int t = blockIdx.x * 256 + threadIdx.x;
    int node = t >> 4;
    int seg = (t & 15) * 8;          // col offset (8 bf16 = 16 B)
    if (node >= N_NODES) return;

    float acc[8];
    {
        short8 v = *(const short8*)(x + (size_t)node * HDIM + seg);
#pragma unroll
        for (int j = 0; j < 8; ++j) acc[j] = bf2f((unsigned short)v[j]);
    }
    int e = rowbeg[node];
    int end = e + deg[node];
    for (; e + 4 <= end; e += 4) {
        int j0 = colidx[e], j1 = colidx[e + 1], j2 = colidx[e + 2], j3 = colidx[e + 3];
        short8 v0 = *(const short8*)(x + (size_t)j0 * HDIM + seg);
        short8 v1 = *(const short8*)(x + (size_t)j1 * HDIM + seg);
        short8 v2 = *(const short8*)(x + (size_t)j2 * HDIM + seg);
        short8 v3 = *(const short8*)(x + (size_t)j3 * HDIM + seg);
#pragma unroll
        for (int j = 0; j < 8; ++j)
            acc[j] += (bf2f((unsigned short)v0[j]) + bf2f((unsigned short)v1[j])) +
                      (bf2f((unsigned short)v2[j]) + bf2f((unsigned short)v3[j]));
    }
    for (; e < end; ++e) {
        int j0 = colidx[e];
        short8 v0 = *(const short8*)(x + (size_t)j0 * HDIM + seg);
#pragma unroll
        for (int j = 0; j < 8; ++j) acc[j] += bf2f((unsigned short)v0[j]);
    }
    short8 o;
#pragma unroll
    for (int j = 0; j < 8; ++j) o[j] = (short)f2bf(acc[j]);
    *(short8*)(y + (size_t)node * HDIM + seg) = o;
}

// ---------------- mlp1: h = y @ W1 + b1, partial BN stats ----------------

__global__ __launch_bounds__(256) void k_mlp1(
    const unsigned short* __restrict__ y,
    const unsigned short* __restrict__ wt,   // [n][k] bf16
    const float* __restrict__ b1,
    unsigned short* __restrict__ hout,
    float* __restrict__ stats)               // [2][128]
{
    __shared__ float s_sum[HDIM], s_sq[HDIM];
    int tid = threadIdx.x;
    if (tid < HDIM) { s_sum[tid] = 0.f; s_sq[tid] = 0.f; }
    __syncthreads();

    int wv = tid >> 6, lane = tid & 63;
    int m = lane & 15, quad = lane >> 4;
    int row0 = blockIdx.x * 64 + wv * 16;
    int arow = row0 + m;

    short8 a[4];
    if (arow < N_NODES) {
#pragma unroll
        for (int kk = 0; kk < 4; ++kk)
            a[kk] = *(const short8*)(y + (size_t)arow * HDIM + kk * 32 + quad * 8);
    } else {
#pragma unroll
        for (int kk = 0; kk < 4; ++kk) a[kk] = (short8)0;
    }

    floatx4 acc[8];
#pragma unroll
    for (int nt = 0; nt < 8; ++nt) {
        floatx4 c = {0.f, 0.f, 0.f, 0.f};
#pragma unroll
        for (int kk = 0; kk < 4; ++kk) {
            short8 b = *(const short8*)(wt + (nt * 16 + m) * HDIM + kk * 32 + quad * 8);
            c = __builtin_amdgcn_mfma_f32_16x16x32_bf16(a[kk], b, c, 0, 0, 0);
        }
        acc[nt] = c;
    }

    int rbase = row0 + quad * 4;
#pragma unroll
    for (int nt = 0; nt < 8; ++nt) {
        int n = nt * 16 + m;
        float bias = b1[n];
        float ssum = 0.f, ssq = 0.f;
#pragma unroll
        for (int r = 0; r < 4; ++r) {
            int row = rbase + r;
            if (row < N_NODES) {
                float val = acc[nt][r] + bias;
                hout[(size_t)row * HDIM + n] = f2bf(val);
                ssum += val;
                ssq += val * val;
            }
        }
        atomicAdd(&s_sum[n], ssum);
        atomicAdd(&s_sq[n], ssq);
    }
    __syncthreads();
    if (tid < HDIM) {
        atomicAdd(&stats[tid], s_sum[tid]);
        atomicAdd(&stats[HDIM + tid], s_sq[tid]);
    }
}

// ---------------- mlp2: x' = relu(BN(h) relu'd @ W2 + b2) ----------------

__global__ __launch_bounds__(256) void k_mlp2(
    const unsigned short* __restrict__ hin,
    const float* __restrict__ stats,
    const float* __restrict__ gamma,
    const float* __restrict__ beta,
    const unsigned short* __restrict__ wt,   // [n][k] bf16
    const float* __restrict__ b2,
    unsigned short* __restrict__ xout)
{
    __shared__ float s_scale[HDIM], s_shift[HDIM];
    int tid = threadIdx.x;
    if (tid < HDIM) {
        float mu = stats[tid] * (1.f / N_NODES);
        float var = stats[HDIM + tid] * (1.f / N_NODES) - mu * mu;
        float sc = gamma[tid] * rsqrtf(var + BN_EPS);
        s_scale[tid] = sc;
        s_shift[tid] = beta[tid] - mu * sc;
    }
    __syncthreads();

    int wv = tid >> 6, lane = tid & 63;
    int m = lane & 15, quad = lane >> 4;
    int row0 = blockIdx.x * 64 + wv * 16;
    int arow = row0 + m;

    short8 a[4];
    if (arow < N_NODES) {
#pragma unroll
        for (int kk = 0; kk < 4; ++kk) {
            short8 v = *(const short8*)(hin + (size_t)arow * HDIM + kk * 32 + quad * 8);
            int c0 = kk * 32 + quad * 8;
            short8 af;
#pragma unroll
            for (int j = 0; j < 8; ++j) {
                float f = fmaxf(bf2f((unsigned short)v[j]) * s_scale[c0 + j] + s_shift[c0 + j], 0.f);
                af[j] = (short)f2bf(f);
            }
            a[kk] = af;
        }
    } else {
#pragma unroll
        for (int kk = 0; kk < 4; ++kk) a[kk] = (short8)0;
    }

    floatx4 acc[8];
#pragma unroll
    for (int nt = 0; nt < 8; ++nt) {
        floatx4 c = {0.f, 0.f, 0.f, 0.f};
#pragma unroll
        for (int kk = 0; kk < 4; ++kk) {
            short8 b = *(const short8*)(wt + (nt * 16 + m) * HDIM + kk * 32 + quad * 8);
            c = __builtin_amdgcn_mfma_f32_16x16x32_bf16(a[kk], b, c, 0, 0, 0);
        }
        acc[nt] = c;
    }

    int rbase = row0 + quad * 4;
#pragma unroll
    for (int nt = 0; nt < 8; ++nt) {
        int n = nt * 16 + m;
        float bias = b2[n];
#pragma unroll
        for (int r = 0; r < 4; ++r) {
            int row = rbase + r;
            if (row < N_NODES) {
                float val = fmaxf(acc[nt][r] + bias, 0.f);
                xout[(size_t)row * HDIM + n] = f2bf(val);
            }
        }
    }
}

// ---------------- pool + head ----------------

__global__ __launch_bounds__(128) void k_poolhead(
    const unsigned short* __restrict__ xf,
    const int* __restrict__ batch,
    const float* __restrict__ hW1, const float* __restrict__ hb1,
    const float* __restrict__ hW2, const float* __restrict__ hb2,
    float* __restrict__ out)
{
    __shared__ float grow[HDIM], th[HDIM];
    int g = blockIdx.x;
    int c = threadIdx.x;

    int lo = 0, hi = N_NODES;
    while (lo < hi) { int mid = (lo + hi) >> 1; if (batch[mid] < g) lo = mid + 1; else hi = mid; }
    int start = lo;
    int lo2 = start, hi2 = N_NODES;
    while (lo2 < hi2) { int mid = (lo2 + hi2) >> 1; if (batch[mid] < g + 1) lo2 = mid + 1; else hi2 = mid; }
    int end = lo2;

    float s = 0.f;
    for (int r = start; r < end; ++r) s += bf2f(xf[(size_t)r * HDIM + c]);
    grow[c] = s;
    __syncthreads();

    float acc = hb1[c];
    for (int k = 0; k < HDIM; ++k) acc += grow[k] * hW1[k * HDIM + c];
    th[c] = fmaxf(acc, 0.f);
    __syncthreads();

    if (c < ODIM) {
        float o = hb2[c];
        for (int k = 0; k < HDIM; ++k) o += th[k] * hW2[k * ODIM + c];
        out[(size_t)g * ODIM + c] = o;
    }
}

// ---------------- launch ----------------

extern "C" void kernel_launch(void* const* d_in, const int* in_sizes, int n_in,
                              void* d_out, int out_size, void* d_ws, size_t ws_size,
                              hipStream_t stream) {
    const float* x        = (const float*)d_in[0];
    const float* conv_W1  = (const float*)d_in[1];
    const float* conv_b1  = (const float*)d_in[2];
    const float* conv_g   = (const float*)d_in[3];
    const float* conv_be  = (const float*)d_in[4];
    const float* conv_W2  = (const float*)d_in[5];
    const float* conv_b2  = (const float*)d_in[6];
    const float* head_W1  = (const float*)d_in[7];
    const float* head_b1  = (const float*)d_in[8];
    const float* head_W2  = (const float*)d_in[9];
    const float* head_b2  = (const float*)d_in[10];
    const int*   edges    = (const int*)d_in[11];   // [0..E)=src, [E..2E)=dst
    const int*   batch    = (const int*)d_in[12];

    char* ws = (char*)d_ws;
    int*            deg     = (int*)(ws + 0);                  // 200000 B
    float*          stats   = (float*)(ws + 200000);           // 3072 B
    int*            counter = (int*)(ws + 203072);             // 4 B
    int*            rowbeg  = (int*)(ws + 203136);             // 200000 B
    int*            cursor  = (int*)(ws + 403136);             // 200000 B
    int*            colidx  = (int*)(ws + 603136);             // 3.2 MB
    unsigned short* wtb     = (unsigned short*)(ws + 3803136); // 196608 B
    unsigned short* xa      = (unsigned short*)(ws + 4000000); // 12.8 MB
    unsigned short* xb      = (unsigned short*)(ws + 16800000);// 12.8 MB
    unsigned short* hbuf    = (unsigned short*)(ws + 29600000);// 12.8 MB
    (void)in_sizes; (void)n_in; (void)out_size; (void)ws_size;

    hipMemsetAsync(ws, 0, 203076, stream);  // deg + stats + counter

    k_hist<<<(N_EDGES + 255) / 256, 256, 0, stream>>>(edges + N_EDGES, deg);
    k_alloc<<<(N_NODES + 255) / 256, 256, 0, stream>>>(deg, rowbeg, cursor, counter);
    k_scatter<<<(N_EDGES + 255) / 256, 256, 0, stream>>>(edges, edges + N_EDGES, cursor, colidx);

    k_cvt<<<(N_NODES * HDIM / 4 + 255) / 256, 256, 0, stream>>>(x, xa);
    k_cvtW<<<(6 * HDIM * HDIM + 255) / 256, 256, 0, stream>>>(conv_W1, conv_W2, wtb);

    const int nblk = (N_NODES + 63) / 64;         // 782
    const int gblk = (N_NODES * 16 + 255) / 256;  // 3125
    unsigned short* cur = xa;
    unsigned short* nxt = xb;
    for (int l = 0; l < NLAYER; ++l) {
        // y goes into nxt (consumed by mlp1 before mlp2 overwrites nxt)
        k_gather<<<gblk, 256, 0, stream>>>(cur, rowbeg, deg, colidx, nxt);
        k_mlp1<<<nblk, 256, 0, stream>>>(nxt, wtb + (2 * l) * HDIM * HDIM,
                                         conv_b1 + l * HDIM, hbuf,
                                         stats + l * 2 * HDIM);
        k_mlp2<<<nblk, 256, 0, stream>>>(hbuf, stats + l * 2 * HDIM,
                                         conv_g + l * HDIM, conv_be + l * HDIM,
                                         wtb + (2 * l + 1) * HDIM * HDIM,
                                         conv_b2 + l * HDIM, nxt);
        unsigned short* t = cur; cur = nxt; nxt = t;
    }

    k_poolhead<<<NGRAPH, 128, 0, stream>>>(cur, batch, head_W1, head_b1,
                                           head_W2, head_b2, (float*)d_out);
}

// Round 4
// 489.406 us; speedup vs baseline: 1.6757x; 1.1048x over previous
//
#include <hip/hip_runtime.h>

#define N_NODES 50000
#define N_EDGES 800000
#define HDIM 128
#define ODIM 64
#define NLAYER 3
#define NGRAPH 512
#define BN_EPS 1e-5f
#define BCAP 48   // bucket capacity; deg ~ Poisson(16), P(deg>=48) ~ 1e-9/node

typedef __attribute__((ext_vector_type(8))) short short8;
typedef __attribute__((ext_vector_type(4))) float floatx4;

static __device__ __forceinline__ unsigned short f2bf(float f) {
    union { float f; unsigned int u; } v; v.f = f;
    unsigned int r = v.u + 0x7FFFu + ((v.u >> 16) & 1u);
    return (unsigned short)(r >> 16);
}
static __device__ __forceinline__ float bf2f(unsigned short s) {
    union { unsigned int u; float f; } v; v.u = ((unsigned int)s) << 16;
    return v.f;
}

// ---------------- bucketed CSR build: one pass, no histogram ----------------

__global__ __launch_bounds__(256) void k_scatter(const int* __restrict__ src,
                                                 const int* __restrict__ dst,
                                                 int* __restrict__ cnt,
                                                 int* __restrict__ colidx) {
    int e = blockIdx.x * 256 + threadIdx.x;
    if (e < N_EDGES) {
        int d = dst[e];
        int pos = atomicAdd(&cnt[d], 1);
        if (pos < BCAP) colidx[d * BCAP + pos] = src[e];
    }
}

// pad each bucket to a multiple of 8 with sentinel row N_NODES (zero row)
__global__ __launch_bounds__(256) void k_pad(const int* __restrict__ cnt,
                                             int* __restrict__ colidx) {
    int n = blockIdx.x * 256 + threadIdx.x;
    if (n < N_NODES) {
        int d = cnt[n]; if (d > BCAP) d = BCAP;
        int end = (d + 7) & ~7;
        for (int i = d; i < end; ++i) colidx[n * BCAP + i] = N_NODES;
    }
}

// ---------------- converts ----------------

__global__ __launch_bounds__(256) void k_cvt(const float* __restrict__ x,
                                             unsigned short* __restrict__ xb) {
    int i = blockIdx.x * 256 + threadIdx.x;
    if (i < N_NODES * HDIM / 4) {
        float4 v = ((const float4*)x)[i];
        ushort4 o = make_ushort4(f2bf(v.x), f2bf(v.y), f2bf(v.z), f2bf(v.w));
        ((ushort4*)xb)[i] = o;
    }
}

// 6 weight matrices [k][n] f32 -> transposed [n][k] bf16; mat 2l=W1[l], 2l+1=W2[l]
__global__ __launch_bounds__(256) void k_cvtW(const float* __restrict__ W1,
                                              const float* __restrict__ W2,
                                              unsigned short* __restrict__ wtb) {
    int idx = blockIdx.x * 256 + threadIdx.x;
    if (idx < 6 * HDIM * HDIM) {
        int mat = idx >> 14;
        int rem = idx & 16383;
        int k = rem >> 7, n = rem & 127;
        int l = mat >> 1;
        const float* W = (mat & 1) ? (W2 + l * HDIM * HDIM) : (W1 + l * HDIM * HDIM);
        wtb[mat * HDIM * HDIM + n * HDIM + k] = f2bf(W[k * HDIM + n]);
    }
}

// ---------------- gather: y[n] = x[n] + sum_{j in N(n)} x[j] ----------------
// 16 lanes per node, 16 B per lane. Buckets padded to x8 -> pure unroll-8 loop,
// 8 outstanding row loads per lane. x has a zero sentinel row at N_NODES.

__global__ __launch_bounds__(256) void k_gather(
    const unsigned short* __restrict__ x,
    const int* __restrict__ cnt,
    const int* __restrict__ colidx,
    unsigned short* __restrict__ y)
{
    int t = blockIdx.x * 256 + threadIdx.x;
    int node = t >> 4;
    int seg = (t & 15) * 8;          // col offset (8 bf16 = 16 B)
    if (node >= N_NODES) return;

    float acc[8];
    {
        short8 v = *(const short8*)(x + (size_t)node * HDIM + seg);
#pragma unroll
        for (int j = 0; j < 8; ++j) acc[j] = bf2f((unsigned short)v[j]);
    }
    int deg = cnt[node]; if (deg > BCAP) deg = BCAP;
    int e = node * BCAP;
    int end = e + ((deg + 7) & ~7);
    for (; e < end; e += 8) {
        int4 c0 = *(const int4*)(colidx + e);
        int4 c1 = *(const int4*)(colidx + e + 4);
        short8 v0 = *(const short8*)(x + (size_t)c0.x * HDIM + seg);
        short8 v1 = *(const short8*)(x + (size_t)c0.y * HDIM + seg);
        short8 v2 = *(const short8*)(x + (size_t)c0.z * HDIM + seg);
        short8 v3 = *(const short8*)(x + (size_t)c0.w * HDIM + seg);
        short8 v4 = *(const short8*)(x + (size_t)c1.x * HDIM + seg);
        short8 v5 = *(const short8*)(x + (size_t)c1.y * HDIM + seg);
        short8 v6 = *(const short8*)(x + (size_t)c1.z * HDIM + seg);
        short8 v7 = *(const short8*)(x + (size_t)c1.w * HDIM + seg);
#pragma unroll
        for (int j = 0; j < 8; ++j)
            acc[j] += ((bf2f((unsigned short)v0[j]) + bf2f((unsigned short)v1[j])) +
                       (bf2f((unsigned short)v2[j]) + bf2f((unsigned short)v3[j]))) +
                      ((bf2f((unsigned short)v4[j]) + bf2f((unsigned short)v5[j])) +
                       (bf2f((unsigned short)v6[j]) + bf2f((unsigned short)v7[j])));
    }
    short8 o;
#pragma unroll
    for (int j = 0; j < 8; ++j) o[j] = (short)f2bf(acc[j]);
    *(short8*)(y + (size_t)node * HDIM + seg) = o;
}

// ---------------- mlp1: h = y @ W1 + b1, partial BN stats ----------------

__global__ __launch_bounds__(256) void k_mlp1(
    const unsigned short* __restrict__ y,
    const unsigned short* __restrict__ wt,   // [n][k] bf16
    const float* __restrict__ b1,
    unsigned short* __restrict__ hout,
    float* __restrict__ stats)               // [2][128]
{
    __shared__ float s_sum[HDIM], s_sq[HDIM];
    int tid = threadIdx.x;
    if (tid < HDIM) { s_sum[tid] = 0.f; s_sq[tid] = 0.f; }
    __syncthreads();

    int wv = tid >> 6, lane = tid & 63;
    int m = lane & 15, quad = lane >> 4;
    int row0 = blockIdx.x * 64 + wv * 16;
    int arow = row0 + m;

    short8 a[4];
    if (arow < N_NODES) {
#pragma unroll
        for (int kk = 0; kk < 4; ++kk)
            a[kk] = *(const short8*)(y + (size_t)arow * HDIM + kk * 32 + quad * 8);
    } else {
#pragma unroll
        for (int kk = 0; kk < 4; ++kk) a[kk] = (short8)0;
    }

    floatx4 acc[8];
#pragma unroll
    for (int nt = 0; nt < 8; ++nt) {
        floatx4 c = {0.f, 0.f, 0.f, 0.f};
#pragma unroll
        for (int kk = 0; kk < 4; ++kk) {
            short8 b = *(const short8*)(wt + (nt * 16 + m) * HDIM + kk * 32 + quad * 8);
            c = __builtin_amdgcn_mfma_f32_16x16x32_bf16(a[kk], b, c, 0, 0, 0);
        }
        acc[nt] = c;
    }

    int rbase = row0 + quad * 4;
#pragma unroll
    for (int nt = 0; nt < 8; ++nt) {
        int n = nt * 16 + m;
        float bias = b1[n];
        float ssum = 0.f, ssq = 0.f;
#pragma unroll
        for (int r = 0; r < 4; ++r) {
            int row = rbase + r;
            if (row < N_NODES) {
                float val = acc[nt][r] + bias;
                hout[(size_t)row * HDIM + n] = f2bf(val);
                ssum += val;
                ssq += val * val;
            }
        }
        atomicAdd(&s_sum[n], ssum);
        atomicAdd(&s_sq[n], ssq);
    }
    __syncthreads();
    if (tid < HDIM) {
        atomicAdd(&stats[tid], s_sum[tid]);
        atomicAdd(&stats[HDIM + tid], s_sq[tid]);
    }
}

// ---------------- mlp2: x' = relu(BN(h) relu'd @ W2 + b2) ----------------

__global__ __launch_bounds__(256) void k_mlp2(
    const unsigned short* __restrict__ hin,
    const float* __restrict__ stats,
    const float* __restrict__ gamma,
    const float* __restrict__ beta,
    const unsigned short* __restrict__ wt,   // [n][k] bf16
    const float* __restrict__ b2,
    unsigned short* __restrict__ xout)
{
    __shared__ float s_scale[HDIM], s_shift[HDIM];
    int tid = threadIdx.x;
    if (tid < HDIM) {
        float mu = stats[tid] * (1.f / N_NODES);
        float var = stats[HDIM + tid] * (1.f / N_NODES) - mu * mu;
        float sc = gamma[tid] * rsqrtf(var + BN_EPS);
        s_scale[tid] = sc;
        s_shift[tid] = beta[tid] - mu * sc;
    }
    __syncthreads();

    int wv = tid >> 6, lane = tid & 63;
    int m = lane & 15, quad = lane >> 4;
    int row0 = blockIdx.x * 64 + wv * 16;
    int arow = row0 + m;

    short8 a[4];
    if (arow < N_NODES) {
#pragma unroll
        for (int kk = 0; kk < 4; ++kk) {
            short8 v = *(const short8*)(hin + (size_t)arow * HDIM + kk * 32 + quad * 8);
            int c0 = kk * 32 + quad * 8;
            short8 af;
#pragma unroll
            for (int j = 0; j < 8; ++j) {
                float f = fmaxf(bf2f((unsigned short)v[j]) * s_scale[c0 + j] + s_shift[c0 + j], 0.f);
                af[j] = (short)f2bf(f);
            }
            a[kk] = af;
        }
    } else {
#pragma unroll
        for (int kk = 0; kk < 4; ++kk) a[kk] = (short8)0;
    }

    floatx4 acc[8];
#pragma unroll
    for (int nt = 0; nt < 8; ++nt) {
        floatx4 c = {0.f, 0.f, 0.f, 0.f};
#pragma unroll
        for (int kk = 0; kk < 4; ++kk) {
            short8 b = *(const short8*)(wt + (nt * 16 + m) * HDIM + kk * 32 + quad * 8);
            c = __builtin_amdgcn_mfma_f32_16x16x32_bf16(a[kk], b, c, 0, 0, 0);
        }
        acc[nt] = c;
    }

    int rbase = row0 + quad * 4;
#pragma unroll
    for (int nt = 0; nt < 8; ++nt) {
        int n = nt * 16 + m;
        float bias = b2[n];
#pragma unroll
        for (int r = 0; r < 4; ++r) {
            int row = rbase + r;
            if (row < N_NODES) {
                float val = fmaxf(acc[nt][r] + bias, 0.f);
                xout[(size_t)row * HDIM + n] = f2bf(val);
            }
        }
    }
}

// ---------------- pool + head ----------------

__global__ __launch_bounds__(128) void k_poolhead(
    const unsigned short* __restrict__ xf,
    const int* __restrict__ batch,
    const float* __restrict__ hW1, const float* __restrict__ hb1,
    const float* __restrict__ hW2, const float* __restrict__ hb2,
    float* __restrict__ out)
{
    __shared__ float grow[HDIM], th[HDIM];
    int g = blockIdx.x;
    int c = threadIdx.x;

    int lo = 0, hi = N_NODES;
    while (lo < hi) { int mid = (lo + hi) >> 1; if (batch[mid] < g) lo = mid + 1; else hi = mid; }
    int start = lo;
    int lo2 = start, hi2 = N_NODES;
    while (lo2 < hi2) { int mid = (lo2 + hi2) >> 1; if (batch[mid] < g + 1) lo2 = mid + 1; else hi2 = mid; }
    int end = lo2;

    float s = 0.f;
    for (int r = start; r < end; ++r) s += bf2f(xf[(size_t)r * HDIM + c]);
    grow[c] = s;
    __syncthreads();

    float acc = hb1[c];
    for (int k = 0; k < HDIM; ++k) acc += grow[k] * hW1[k * HDIM + c];
    th[c] = fmaxf(acc, 0.f);
    __syncthreads();

    if (c < ODIM) {
        float o = hb2[c];
        for (int k = 0; k < HDIM; ++k) o += th[k] * hW2[k * ODIM + c];
        out[(size_t)g * ODIM + c] = o;
    }
}

// ---------------- launch ----------------

extern "C" void kernel_launch(void* const* d_in, const int* in_sizes, int n_in,
                              void* d_out, int out_size, void* d_ws, size_t ws_size,
                              hipStream_t stream) {
    const float* x        = (const float*)d_in[0];
    const float* conv_W1  = (const float*)d_in[1];
    const float* conv_b1  = (const float*)d_in[2];
    const float* conv_g   = (const float*)d_in[3];
    const float* conv_be  = (const float*)d_in[4];
    const float* conv_W2  = (const float*)d_in[5];
    const float* conv_b2  = (const float*)d_in[6];
    const float* head_W1  = (const float*)d_in[7];
    const float* head_b1  = (const float*)d_in[8];
    const float* head_W2  = (const float*)d_in[9];
    const float* head_b2  = (const float*)d_in[10];
    const int*   edges    = (const int*)d_in[11];   // [0..E)=src, [E..2E)=dst
    const int*   batch    = (const int*)d_in[12];

    char* ws = (char*)d_ws;
    int*            cnt    = (int*)(ws + 0);                   // 200,000 B
    float*          stats  = (float*)(ws + 200000);            // 3,072 B
    int*            colidx = (int*)(ws + 203072);              // 50000*48*4 = 9,600,000 B
    unsigned short* wtb    = (unsigned short*)(ws + 9803072);  // 196,608 B
    unsigned short* xa     = (unsigned short*)(ws + 10000000); // (N+1) rows = 12,800,256 B
    unsigned short* xb     = (unsigned short*)(ws + 22800384); // 12,800,256 B
    (void)in_sizes; (void)n_in; (void)out_size; (void)ws_size;

    hipMemsetAsync(ws, 0, 203072, stream);                     // cnt + stats
    hipMemsetAsync(ws + 10000000 + (size_t)N_NODES * HDIM * 2, 0, HDIM * 2, stream);  // xa sentinel
    hipMemsetAsync(ws + 22800384 + (size_t)N_NODES * HDIM * 2, 0, HDIM * 2, stream);  // xb sentinel

    k_scatter<<<(N_EDGES + 255) / 256, 256, 0, stream>>>(edges, edges + N_EDGES, cnt, colidx);
    k_pad<<<(N_NODES + 255) / 256, 256, 0, stream>>>(cnt, colidx);

    k_cvt<<<(N_NODES * HDIM / 4 + 255) / 256, 256, 0, stream>>>(x, xa);
    k_cvtW<<<(6 * HDIM * HDIM + 255) / 256, 256, 0, stream>>>(conv_W1, conv_W2, wtb);

    const int nblk = (N_NODES + 63) / 64;         // 782
    const int gblk = (N_NODES * 16 + 255) / 256;  // 3125
    unsigned short* cur = xa;
    unsigned short* nxt = xb;
    for (int l = 0; l < NLAYER; ++l) {
        // gather: cur -> nxt (y). mlp1: nxt -> cur (h; cur's x is dead).
        // mlp2: cur (h) -> nxt (x'). swap.
        k_gather<<<gblk, 256, 0, stream>>>(cur, cnt, colidx, nxt);
        k_mlp1<<<nblk, 256, 0, stream>>>(nxt, wtb + (2 * l) * HDIM * HDIM,
                                         conv_b1 + l * HDIM, cur,
                                         stats + l * 2 * HDIM);
        k_mlp2<<<nblk, 256, 0, stream>>>(cur, stats + l * 2 * HDIM,
                                         conv_g + l * HDIM, conv_be + l * HDIM,
                                         wtb + (2 * l + 1) * HDIM * HDIM,
                                         conv_b2 + l * HDIM, nxt);
        unsigned short* t = cur; cur = nxt; nxt = t;
    }

    k_poolhead<<<NGRAPH, 128, 0, stream>>>(cur, batch, head_W1, head_b1,
                                           head_W2, head_b2, (float*)d_out);
}

// Round 5
// 482.011 us; speedup vs baseline: 1.7014x; 1.0153x over previous
//
#include <hip/hip_runtime.h>

#define N_NODES 50000
#define N_EDGES 800000
#define HDIM 128
#define ODIM 64
#define NLAYER 3
#define NGRAPH 512
#define BN_EPS 1e-5f
#define BCAP 48     // bucket capacity; deg ~ Poisson(16), P(deg>=48) ~ 1e-9/node
#define NBLK 782    // mlp grid: ceil(50000/64)
#define PBLK 800    // partial-stats pitch (>= NBLK)

typedef __attribute__((ext_vector_type(8))) short short8;
typedef __attribute__((ext_vector_type(4))) float floatx4;

static __device__ __forceinline__ unsigned short f2bf(float f) {
    union { float f; unsigned int u; } v; v.f = f;
    unsigned int r = v.u + 0x7FFFu + ((v.u >> 16) & 1u);
    return (unsigned short)(r >> 16);
}
static __device__ __forceinline__ float bf2f(unsigned short s) {
    union { unsigned int u; float f; } v; v.u = ((unsigned int)s) << 16;
    return v.f;
}

// ---------------- bucketed CSR build: one pass, no histogram ----------------

__global__ __launch_bounds__(256) void k_scatter(const int* __restrict__ src,
                                                 const int* __restrict__ dst,
                                                 int* __restrict__ cnt,
                                                 int* __restrict__ colidx) {
    int e = blockIdx.x * 256 + threadIdx.x;
    if (e < N_EDGES) {
        int d = dst[e];
        int pos = atomicAdd(&cnt[d], 1);
        if (pos < BCAP) colidx[d * BCAP + pos] = src[e];
    }
}

// pad each bucket to a multiple of 8 with sentinel row N_NODES (zero row)
__global__ __launch_bounds__(256) void k_pad(const int* __restrict__ cnt,
                                             int* __restrict__ colidx) {
    int n = blockIdx.x * 256 + threadIdx.x;
    if (n < N_NODES) {
        int d = cnt[n]; if (d > BCAP) d = BCAP;
        int end = (d + 7) & ~7;
        for (int i = d; i < end; ++i) colidx[n * BCAP + i] = N_NODES;
    }
}

// ---------------- converts ----------------

__global__ __launch_bounds__(256) void k_cvt(const float* __restrict__ x,
                                             unsigned short* __restrict__ xb) {
    int i = blockIdx.x * 256 + threadIdx.x;
    if (i < N_NODES * HDIM / 4) {
        float4 v = ((const float4*)x)[i];
        ushort4 o = make_ushort4(f2bf(v.x), f2bf(v.y), f2bf(v.z), f2bf(v.w));
        ((ushort4*)xb)[i] = o;
    }
}

// 6 weight matrices [k][n] f32 -> transposed [n][k] bf16; mat 2l=W1[l], 2l+1=W2[l]
__global__ __launch_bounds__(256) void k_cvtW(const float* __restrict__ W1,
                                              const float* __restrict__ W2,
                                              unsigned short* __restrict__ wtb) {
    int idx = blockIdx.x * 256 + threadIdx.x;
    if (idx < 6 * HDIM * HDIM) {
        int mat = idx >> 14;
        int rem = idx & 16383;
        int k = rem >> 7, n = rem & 127;
        int l = mat >> 1;
        const float* W = (mat & 1) ? (W2 + l * HDIM * HDIM) : (W1 + l * HDIM * HDIM);
        wtb[mat * HDIM * HDIM + n * HDIM + k] = f2bf(W[k * HDIM + n]);
    }
}

// ---------------- gather: y[n] = x[n] + sum_{j in N(n)} x[j] ----------------
// 16 lanes per node, 16 B per lane. Buckets padded to x8 -> pure unroll-8 loop.

__global__ __launch_bounds__(256) void k_gather(
    const unsigned short* __restrict__ x,
    const int* __restrict__ cnt,
    const int* __restrict__ colidx,
    unsigned short* __restrict__ y)
{
    int t = blockIdx.x * 256 + threadIdx.x;
    int node = t >> 4;
    int seg = (t & 15) * 8;          // col offset (8 bf16 = 16 B)
    if (node >= N_NODES) return;

    float acc[8];
    {
        short8 v = *(const short8*)(x + (size_t)node * HDIM + seg);
#pragma unroll
        for (int j = 0; j < 8; ++j) acc[j] = bf2f((unsigned short)v[j]);
    }
    int deg = cnt[node]; if (deg > BCAP) deg = BCAP;
    int e = node * BCAP;
    int end = e + ((deg + 7) & ~7);
    for (; e < end; e += 8) {
        int4 c0 = *(const int4*)(colidx + e);
        int4 c1 = *(const int4*)(colidx + e + 4);
        short8 v0 = *(const short8*)(x + (size_t)c0.x * HDIM + seg);
        short8 v1 = *(const short8*)(x + (size_t)c0.y * HDIM + seg);
        short8 v2 = *(const short8*)(x + (size_t)c0.z * HDIM + seg);
        short8 v3 = *(const short8*)(x + (size_t)c0.w * HDIM + seg);
        short8 v4 = *(const short8*)(x + (size_t)c1.x * HDIM + seg);
        short8 v5 = *(const short8*)(x + (size_t)c1.y * HDIM + seg);
        short8 v6 = *(const short8*)(x + (size_t)c1.z * HDIM + seg);
        short8 v7 = *(const short8*)(x + (size_t)c1.w * HDIM + seg);
#pragma unroll
        for (int j = 0; j < 8; ++j)
            acc[j] += ((bf2f((unsigned short)v0[j]) + bf2f((unsigned short)v1[j])) +
                       (bf2f((unsigned short)v2[j]) + bf2f((unsigned short)v3[j]))) +
                      ((bf2f((unsigned short)v4[j]) + bf2f((unsigned short)v5[j])) +
                       (bf2f((unsigned short)v6[j]) + bf2f((unsigned short)v7[j])));
    }
    short8 o;
#pragma unroll
    for (int j = 0; j < 8; ++j) o[j] = (short)f2bf(acc[j]);
    *(short8*)(y + (size_t)node * HDIM + seg) = o;
}

// ---------------- mlp1: h = y @ W1 + b1, per-block partial BN stats ----------
// NO global atomics: block partials -> p[col][block], reduced by k_stats.
// (R4 post-mortem: 200K atomics onto 16 cache lines serialized ~50 us.)

__global__ __launch_bounds__(256) void k_mlp1(
    const unsigned short* __restrict__ y,
    const unsigned short* __restrict__ wt,   // [n][k] bf16
    const float* __restrict__ b1,
    unsigned short* __restrict__ hout,
    float* __restrict__ pout)                // [256][PBLK] partials
{
    __shared__ float s_sum[HDIM], s_sq[HDIM];
    int tid = threadIdx.x;
    if (tid < HDIM) { s_sum[tid] = 0.f; s_sq[tid] = 0.f; }
    __syncthreads();

    int wv = tid >> 6, lane = tid & 63;
    int m = lane & 15, quad = lane >> 4;
    int row0 = blockIdx.x * 64 + wv * 16;
    int arow = row0 + m;

    short8 a[4];
    if (arow < N_NODES) {
#pragma unroll
        for (int kk = 0; kk < 4; ++kk)
            a[kk] = *(const short8*)(y + (size_t)arow * HDIM + kk * 32 + quad * 8);
    } else {
#pragma unroll
        for (int kk = 0; kk < 4; ++kk) a[kk] = (short8)0;
    }

    floatx4 acc[8];
#pragma unroll
    for (int nt = 0; nt < 8; ++nt) {
        floatx4 c = {0.f, 0.f, 0.f, 0.f};
#pragma unroll
        for (int kk = 0; kk < 4; ++kk) {
            short8 b = *(const short8*)(wt + (nt * 16 + m) * HDIM + kk * 32 + quad * 8);
            c = __builtin_amdgcn_mfma_f32_16x16x32_bf16(a[kk], b, c, 0, 0, 0);
        }
        acc[nt] = c;
    }

    int rbase = row0 + quad * 4;
#pragma unroll
    for (int nt = 0; nt < 8; ++nt) {
        int n = nt * 16 + m;
        float bias = b1[n];
        float ssum = 0.f, ssq = 0.f;
#pragma unroll
        for (int r = 0; r < 4; ++r) {
            int row = rbase + r;
            if (row < N_NODES) {
                float val = acc[nt][r] + bias;
                hout[(size_t)row * HDIM + n] = f2bf(val);
                ssum += val;
                ssq += val * val;
            }
        }
        atomicAdd(&s_sum[n], ssum);
        atomicAdd(&s_sq[n], ssq);
    }
    __syncthreads();
    if (tid < HDIM) {
        pout[(size_t)tid * PBLK + blockIdx.x] = s_sum[tid];
        pout[(size_t)(tid + HDIM) * PBLK + blockIdx.x] = s_sq[tid];
    }
}

// ---------------- stats: reduce partials, one block per column ----------------

__global__ __launch_bounds__(256) void k_stats(const float* __restrict__ p,
                                               float* __restrict__ stats) {
    int c = blockIdx.x;          // 0..255 (128 sum + 128 sumsq)
    int tid = threadIdx.x;
    const float* col = p + (size_t)c * PBLK;
    float s = 0.f;
    for (int i = tid; i < NBLK; i += 256) s += col[i];
#pragma unroll
    for (int off = 32; off; off >>= 1) s += __shfl_down(s, off, 64);
    __shared__ float red[4];
    if ((tid & 63) == 0) red[tid >> 6] = s;
    __syncthreads();
    if (tid == 0) stats[c] = red[0] + red[1] + red[2] + red[3];
}

// ---------------- mlp2: x' = relu(BN(h) relu'd @ W2 + b2) ----------------

__global__ __launch_bounds__(256) void k_mlp2(
    const unsigned short* __restrict__ hin,
    const float* __restrict__ stats,
    const float* __restrict__ gamma,
    const float* __restrict__ beta,
    const unsigned short* __restrict__ wt,   // [n][k] bf16
    const float* __restrict__ b2,
    unsigned short* __restrict__ xout)
{
    __shared__ float s_scale[HDIM], s_shift[HDIM];
    int tid = threadIdx.x;
    if (tid < HDIM) {
        float mu = stats[tid] * (1.f / N_NODES);
        float var = stats[HDIM + tid] * (1.f / N_NODES) - mu * mu;
        float sc = gamma[tid] * rsqrtf(var + BN_EPS);
        s_scale[tid] = sc;
        s_shift[tid] = beta[tid] - mu * sc;
    }
    __syncthreads();

    int wv = tid >> 6, lane = tid & 63;
    int m = lane & 15, quad = lane >> 4;
    int row0 = blockIdx.x * 64 + wv * 16;
    int arow = row0 + m;

    short8 a[4];
    if (arow < N_NODES) {
#pragma unroll
        for (int kk = 0; kk < 4; ++kk) {
            short8 v = *(const short8*)(hin + (size_t)arow * HDIM + kk * 32 + quad * 8);
            int c0 = kk * 32 + quad * 8;
            short8 af;
#pragma unroll
            for (int j = 0; j < 8; ++j) {
                float f = fmaxf(bf2f((unsigned short)v[j]) * s_scale[c0 + j] + s_shift[c0 + j], 0.f);
                af[j] = (short)f2bf(f);
            }
            a[kk] = af;
        }
    } else {
#pragma unroll
        for (int kk = 0; kk < 4; ++kk) a[kk] = (short8)0;
    }

    floatx4 acc[8];
#pragma unroll
    for (int nt = 0; nt < 8; ++nt) {
        floatx4 c = {0.f, 0.f, 0.f, 0.f};
#pragma unroll
        for (int kk = 0; kk < 4; ++kk) {
            short8 b = *(const short8*)(wt + (nt * 16 + m) * HDIM + kk * 32 + quad * 8);
            c = __builtin_amdgcn_mfma_f32_16x16x32_bf16(a[kk], b, c, 0, 0, 0);
        }
        acc[nt] = c;
    }

    int rbase = row0 + quad * 4;
#pragma unroll
    for (int nt = 0; nt < 8; ++nt) {
        int n = nt * 16 + m;
        float bias = b2[n];
#pragma unroll
        for (int r = 0; r < 4; ++r) {
            int row = rbase + r;
            if (row < N_NODES) {
                float val = fmaxf(acc[nt][r] + bias, 0.f);
                xout[(size_t)row * HDIM + n] = f2bf(val);
            }
        }
    }
}

// ---------------- pool + head ----------------

__global__ __launch_bounds__(128) void k_poolhead(
    const unsigned short* __restrict__ xf,
    const int* __restrict__ batch,
    const float* __restrict__ hW1, const float* __restrict__ hb1,
    const float* __restrict__ hW2, const float* __restrict__ hb2,
    float* __restrict__ out)
{
    __shared__ float grow[HDIM], th[HDIM];
    int g = blockIdx.x;
    int c = threadIdx.x;

    int lo = 0, hi = N_NODES;
    while (lo < hi) { int mid = (lo + hi) >> 1; if (batch[mid] < g) lo = mid + 1; else hi = mid; }
    int start = lo;
    int lo2 = start, hi2 = N_NODES;
    while (lo2 < hi2) { int mid = (lo2 + hi2) >> 1; if (batch[mid] < g + 1) lo2 = mid + 1; else hi2 = mid; }
    int end = lo2;

    float s = 0.f;
    for (int r = start; r < end; ++r) s += bf2f(xf[(size_t)r * HDIM + c]);
    grow[c] = s;
    __syncthreads();

    float acc = hb1[c];
    for (int k = 0; k < HDIM; ++k) acc += grow[k] * hW1[k * HDIM + c];
    th[c] = fmaxf(acc, 0.f);
    __syncthreads();

    if (c < ODIM) {
        float o = hb2[c];
        for (int k = 0; k < HDIM; ++k) o += th[k] * hW2[k * ODIM + c];
        out[(size_t)g * ODIM + c] = o;
    }
}

// ---------------- launch ----------------

extern "C" void kernel_launch(void* const* d_in, const int* in_sizes, int n_in,
                              void* d_out, int out_size, void* d_ws, size_t ws_size,
                              hipStream_t stream) {
    const float* x        = (const float*)d_in[0];
    const float* conv_W1  = (const float*)d_in[1];
    const float* conv_b1  = (const float*)d_in[2];
    const float* conv_g   = (const float*)d_in[3];
    const float* conv_be  = (const float*)d_in[4];
    const float* conv_W2  = (const float*)d_in[5];
    const float* conv_b2  = (const float*)d_in[6];
    const float* head_W1  = (const float*)d_in[7];
    const float* head_b1  = (const float*)d_in[8];
    const float* head_W2  = (const float*)d_in[9];
    const float* head_b2  = (const float*)d_in[10];
    const int*   edges    = (const int*)d_in[11];   // [0..E)=src, [E..2E)=dst
    const int*   batch    = (const int*)d_in[12];

    char* ws = (char*)d_ws;
    int*            cnt    = (int*)(ws + 0);                   // 200,000 B
    float*          stats  = (float*)(ws + 200000);            // 3*256*4 = 3,072 B
    int*            colidx = (int*)(ws + 203072);              // 9,600,000 B
    unsigned short* wtb    = (unsigned short*)(ws + 9803072);  // 196,608 B
    float*          part   = (float*)(ws + 10000000);          // 256*PBLK*4 = 819,200 B
    unsigned short* xa     = (unsigned short*)(ws + 10819200); // (N+1) rows = 12,800,256 B
    unsigned short* xb     = (unsigned short*)(ws + 23619584); // 12,800,256 B
    (void)in_sizes; (void)n_in; (void)out_size; (void)ws_size;

    hipMemsetAsync(ws, 0, 200000, stream);                     // cnt
    hipMemsetAsync(ws + 10819200 + (size_t)N_NODES * HDIM * 2, 0, HDIM * 2, stream);  // xa sentinel
    hipMemsetAsync(ws + 23619584 + (size_t)N_NODES * HDIM * 2, 0, HDIM * 2, stream);  // xb sentinel

    k_scatter<<<(N_EDGES + 255) / 256, 256, 0, stream>>>(edges, edges + N_EDGES, cnt, colidx);
    k_pad<<<(N_NODES + 255) / 256, 256, 0, stream>>>(cnt, colidx);

    k_cvt<<<(N_NODES * HDIM / 4 + 255) / 256, 256, 0, stream>>>(x, xa);
    k_cvtW<<<(6 * HDIM * HDIM + 255) / 256, 256, 0, stream>>>(conv_W1, conv_W2, wtb);

    const int gblk = (N_NODES * 16 + 255) / 256;  // 3125
    unsigned short* cur = xa;
    unsigned short* nxt = xb;
    for (int l = 0; l < NLAYER; ++l) {
        // gather: cur -> nxt (y). mlp1: nxt -> cur (h; cur's x is dead).
        // mlp2: cur (h) -> nxt (x'). swap.
        k_gather<<<gblk, 256, 0, stream>>>(cur, cnt, colidx, nxt);
        k_mlp1<<<NBLK, 256, 0, stream>>>(nxt, wtb + (2 * l) * HDIM * HDIM,
                                         conv_b1 + l * HDIM, cur, part);
        k_stats<<<256, 256, 0, stream>>>(part, stats + l * 256);
        k_mlp2<<<NBLK, 256, 0, stream>>>(cur, stats + l * 256,
                                         conv_g + l * HDIM, conv_be + l * HDIM,
                                         wtb + (2 * l + 1) * HDIM * HDIM,
                                         conv_b2 + l * HDIM, nxt);
        unsigned short* t = cur; cur = nxt; nxt = t;
    }

    k_poolhead<<<NGRAPH, 128, 0, stream>>>(cur, batch, head_W1, head_b1,
                                           head_W2, head_b2, (float*)d_out);
}

// Round 6
// 476.375 us; speedup vs baseline: 1.7215x; 1.0118x over previous
//
#include <hip/hip_runtime.h>

#define N_NODES 50000
#define N_EDGES 800000
#define HDIM 128
#define ODIM 64
#define NLAYER 3
#define NGRAPH 512
#define BN_EPS 1e-5f
#define BCAP 48      // bucket capacity; deg ~ Poisson(16), P(deg>=48) ~ 1e-9/node
#define NBLK 782     // mlp grid: ceil(50000/64)
#define PBLK 800     // partial-stats pitch (>= NBLK)
#define CSTRIDE 16   // cnt padded to one counter per 64B line (atomic de-serialization)
#define HPITCH 136   // LDS pitch for head t-tile

// k_prep block-range partition
#define SCAT_BLK 782            // 800000 edges / 4 per thread / 256
#define CVT_BLK 6250            // 1.6M float4
#define CVTW_BLK 480            // 122880 weight elems

typedef __attribute__((ext_vector_type(8))) short short8;
typedef __attribute__((ext_vector_type(4))) float floatx4;

static __device__ __forceinline__ unsigned short f2bf(float f) {
    union { float f; unsigned int u; } v; v.f = f;
    unsigned int r = v.u + 0x7FFFu + ((v.u >> 16) & 1u);
    return (unsigned short)(r >> 16);
}
static __device__ __forceinline__ float bf2f(unsigned short s) {
    union { unsigned int u; float f; } v; v.u = ((unsigned int)s) << 16;
    return v.f;
}

// ---- fused prep: scatter (4 edges/thread, padded counters) + cvt + cvtW ----

__global__ __launch_bounds__(256) void k_prep(
    const int* __restrict__ src, const int* __restrict__ dst,
    int* __restrict__ cnt, int* __restrict__ colidx,
    const float* __restrict__ x, unsigned short* __restrict__ xb,
    const float* __restrict__ W1, const float* __restrict__ W2,
    const float* __restrict__ hW1, const float* __restrict__ hW2,
    unsigned short* __restrict__ wtb)
{
    int b = blockIdx.x;
    int tid = threadIdx.x;
    if (b < SCAT_BLK) {
        int base = (b * 256 + tid) * 4;
        if (base < N_EDGES) {
            int4 s4 = *(const int4*)(src + base);
            int4 d4 = *(const int4*)(dst + base);
            int p0 = atomicAdd(&cnt[d4.x * CSTRIDE], 1);
            int p1 = atomicAdd(&cnt[d4.y * CSTRIDE], 1);
            int p2 = atomicAdd(&cnt[d4.z * CSTRIDE], 1);
            int p3 = atomicAdd(&cnt[d4.w * CSTRIDE], 1);
            if (p0 < BCAP) colidx[d4.x * BCAP + p0] = s4.x;
            if (p1 < BCAP) colidx[d4.y * BCAP + p1] = s4.y;
            if (p2 < BCAP) colidx[d4.z * BCAP + p2] = s4.z;
            if (p3 < BCAP) colidx[d4.w * BCAP + p3] = s4.w;
        }
    } else if (b < SCAT_BLK + CVT_BLK) {
        int i = (b - SCAT_BLK) * 256 + tid;
        if (i < N_NODES * HDIM / 4) {
            float4 v = ((const float4*)x)[i];
            ushort4 o = make_ushort4(f2bf(v.x), f2bf(v.y), f2bf(v.z), f2bf(v.w));
            ((ushort4*)xb)[i] = o;
        }
    } else {
        int idx = (b - SCAT_BLK - CVT_BLK) * 256 + tid;
        if (idx < 6 * HDIM * HDIM) {
            // conv weights: mat 2l=W1[l], 2l+1=W2[l]; [k][n] -> [n][k] bf16
            int mat = idx >> 14;
            int rem = idx & 16383;
            int k = rem >> 7, n = rem & 127;
            int l = mat >> 1;
            const float* W = (mat & 1) ? (W2 + l * HDIM * HDIM) : (W1 + l * HDIM * HDIM);
            wtb[mat * HDIM * HDIM + n * HDIM + k] = f2bf(W[k * HDIM + n]);
        } else if (idx < 7 * HDIM * HDIM) {
            int j = idx - 6 * HDIM * HDIM;
            int n = j >> 7, k = j & 127;
            wtb[idx] = f2bf(hW1[k * HDIM + n]);
        } else if (idx < 7 * HDIM * HDIM + ODIM * HDIM) {
            int j = idx - 7 * HDIM * HDIM;
            int n = j >> 7, k = j & 127;   // n in [0,64)
            wtb[idx] = f2bf(hW2[k * ODIM + n]);
        }
    }
}

// pad each bucket to a multiple of 8 with sentinel row N_NODES (zero row)
__global__ __launch_bounds__(256) void k_pad(const int* __restrict__ cnt,
                                             int* __restrict__ colidx) {
    int n = blockIdx.x * 256 + threadIdx.x;
    if (n < N_NODES) {
        int d = cnt[n * CSTRIDE]; if (d > BCAP) d = BCAP;
        int end = (d + 7) & ~7;
        for (int i = d; i < end; ++i) colidx[n * BCAP + i] = N_NODES;
    }
}

// ---------------- gather: y[n] = x[n] + sum_{j in N(n)} x[j] ----------------

__global__ __launch_bounds__(256) void k_gather(
    const unsigned short* __restrict__ x,
    const int* __restrict__ cnt,
    const int* __restrict__ colidx,
    unsigned short* __restrict__ y)
{
    int t = blockIdx.x * 256 + threadIdx.x;
    int node = t >> 4;
    int seg = (t & 15) * 8;          // col offset (8 bf16 = 16 B)
    if (node >= N_NODES) return;

    float acc[8];
    {
        short8 v = *(const short8*)(x + (size_t)node * HDIM + seg);
#pragma unroll
        for (int j = 0; j < 8; ++j) acc[j] = bf2f((unsigned short)v[j]);
    }
    int deg = cnt[node * CSTRIDE]; if (deg > BCAP) deg = BCAP;
    int e = node * BCAP;
    int end = e + ((deg + 7) & ~7);
    for (; e < end; e += 8) {
        int4 c0 = *(const int4*)(colidx + e);
        int4 c1 = *(const int4*)(colidx + e + 4);
        short8 v0 = *(const short8*)(x + (size_t)c0.x * HDIM + seg);
        short8 v1 = *(const short8*)(x + (size_t)c0.y * HDIM + seg);
        short8 v2 = *(const short8*)(x + (size_t)c0.z * HDIM + seg);
        short8 v3 = *(const short8*)(x + (size_t)c0.w * HDIM + seg);
        short8 v4 = *(const short8*)(x + (size_t)c1.x * HDIM + seg);
        short8 v5 = *(const short8*)(x + (size_t)c1.y * HDIM + seg);
        short8 v6 = *(const short8*)(x + (size_t)c1.z * HDIM + seg);
        short8 v7 = *(const short8*)(x + (size_t)c1.w * HDIM + seg);
#pragma unroll
        for (int j = 0; j < 8; ++j)
            acc[j] += ((bf2f((unsigned short)v0[j]) + bf2f((unsigned short)v1[j])) +
                       (bf2f((unsigned short)v2[j]) + bf2f((unsigned short)v3[j]))) +
                      ((bf2f((unsigned short)v4[j]) + bf2f((unsigned short)v5[j])) +
                       (bf2f((unsigned short)v6[j]) + bf2f((unsigned short)v7[j])));
    }
    short8 o;
#pragma unroll
    for (int j = 0; j < 8; ++j) o[j] = (short)f2bf(acc[j]);
    *(short8*)(y + (size_t)node * HDIM + seg) = o;
}

// ---------------- mlp1: h = y @ W1 + b1, per-block partial BN stats ----------

__global__ __launch_bounds__(256) void k_mlp1(
    const unsigned short* __restrict__ y,
    const unsigned short* __restrict__ wt,   // [n][k] bf16
    const float* __restrict__ b1,
    unsigned short* __restrict__ hout,
    float* __restrict__ pout)                // [256][PBLK] partials
{
    __shared__ float s_sum[HDIM], s_sq[HDIM];
    int tid = threadIdx.x;
    if (tid < HDIM) { s_sum[tid] = 0.f; s_sq[tid] = 0.f; }
    __syncthreads();

    int wv = tid >> 6, lane = tid & 63;
    int m = lane & 15, quad = lane >> 4;
    int row0 = blockIdx.x * 64 + wv * 16;
    int arow = row0 + m;

    short8 a[4];
    if (arow < N_NODES) {
#pragma unroll
        for (int kk = 0; kk < 4; ++kk)
            a[kk] = *(const short8*)(y + (size_t)arow * HDIM + kk * 32 + quad * 8);
    } else {
#pragma unroll
        for (int kk = 0; kk < 4; ++kk) a[kk] = (short8)0;
    }

    floatx4 acc[8];
#pragma unroll
    for (int nt = 0; nt < 8; ++nt) {
        floatx4 c = {0.f, 0.f, 0.f, 0.f};
#pragma unroll
        for (int kk = 0; kk < 4; ++kk) {
            short8 b = *(const short8*)(wt + (nt * 16 + m) * HDIM + kk * 32 + quad * 8);
            c = __builtin_amdgcn_mfma_f32_16x16x32_bf16(a[kk], b, c, 0, 0, 0);
        }
        acc[nt] = c;
    }

    int rbase = row0 + quad * 4;
#pragma unroll
    for (int nt = 0; nt < 8; ++nt) {
        int n = nt * 16 + m;
        float bias = b1[n];
        float ssum = 0.f, ssq = 0.f;
#pragma unroll
        for (int r = 0; r < 4; ++r) {
            int row = rbase + r;
            if (row < N_NODES) {
                float val = acc[nt][r] + bias;
                hout[(size_t)row * HDIM + n] = f2bf(val);
                ssum += val;
                ssq += val * val;
            }
        }
        atomicAdd(&s_sum[n], ssum);
        atomicAdd(&s_sq[n], ssq);
    }
    __syncthreads();
    if (tid < HDIM) {
        pout[(size_t)tid * PBLK + blockIdx.x] = s_sum[tid];
        pout[(size_t)(tid + HDIM) * PBLK + blockIdx.x] = s_sq[tid];
    }
}

// ---------------- stats: reduce partials, one block per column ----------------

__global__ __launch_bounds__(256) void k_stats(const float* __restrict__ p,
                                               float* __restrict__ stats) {
    int c = blockIdx.x;          // 0..255 (128 sum + 128 sumsq)
    int tid = threadIdx.x;
    const float* col = p + (size_t)c * PBLK;
    float s = 0.f;
    for (int i = tid; i < NBLK; i += 256) s += col[i];
#pragma unroll
    for (int off = 32; off; off >>= 1) s += __shfl_down(s, off, 64);
    __shared__ float red[4];
    if ((tid & 63) == 0) red[tid >> 6] = s;
    __syncthreads();
    if (tid == 0) stats[c] = red[0] + red[1] + red[2] + red[3];
}

// ---------------- mlp2: x' = relu(BN(h) relu'd @ W2 + b2) ----------------

__global__ __launch_bounds__(256) void k_mlp2(
    const unsigned short* __restrict__ hin,
    const float* __restrict__ stats,
    const float* __restrict__ gamma,
    const float* __restrict__ beta,
    const unsigned short* __restrict__ wt,   // [n][k] bf16
    const float* __restrict__ b2,
    unsigned short* __restrict__ xout)
{
    __shared__ float s_scale[HDIM], s_shift[HDIM];
    int tid = threadIdx.x;
    if (tid < HDIM) {
        float mu = stats[tid] * (1.f / N_NODES);
        float var = stats[HDIM + tid] * (1.f / N_NODES) - mu * mu;
        float sc = gamma[tid] * rsqrtf(var + BN_EPS);
        s_scale[tid] = sc;
        s_shift[tid] = beta[tid] - mu * sc;
    }
    __syncthreads();

    int wv = tid >> 6, lane = tid & 63;
    int m = lane & 15, quad = lane >> 4;
    int row0 = blockIdx.x * 64 + wv * 16;
    int arow = row0 + m;

    short8 a[4];
    if (arow < N_NODES) {
#pragma unroll
        for (int kk = 0; kk < 4; ++kk) {
            short8 v = *(const short8*)(hin + (size_t)arow * HDIM + kk * 32 + quad * 8);
            int c0 = kk * 32 + quad * 8;
            short8 af;
#pragma unroll
            for (int j = 0; j < 8; ++j) {
                float f = fmaxf(bf2f((unsigned short)v[j]) * s_scale[c0 + j] + s_shift[c0 + j], 0.f);
                af[j] = (short)f2bf(f);
            }
            a[kk] = af;
        }
    } else {
#pragma unroll
        for (int kk = 0; kk < 4; ++kk) a[kk] = (short8)0;
    }

    floatx4 acc[8];
#pragma unroll
    for (int nt = 0; nt < 8; ++nt) {
        floatx4 c = {0.f, 0.f, 0.f, 0.f};
#pragma unroll
        for (int kk = 0; kk < 4; ++kk) {
            short8 b = *(const short8*)(wt + (nt * 16 + m) * HDIM + kk * 32 + quad * 8);
            c = __builtin_amdgcn_mfma_f32_16x16x32_bf16(a[kk], b, c, 0, 0, 0);
        }
        acc[nt] = c;
    }

    int rbase = row0 + quad * 4;
#pragma unroll
    for (int nt = 0; nt < 8; ++nt) {
        int n = nt * 16 + m;
        float bias = b2[n];
#pragma unroll
        for (int r = 0; r < 4; ++r) {
            int row = rbase + r;
            if (row < N_NODES) {
                float val = fmaxf(acc[nt][r] + bias, 0.f);
                xout[(size_t)row * HDIM + n] = f2bf(val);
            }
        }
    }
}

// ---------------- pool: g[gid] = sum of node rows (bf16 out) ----------------
// 256 threads/graph: 16 col-segs x 16 rows in flight.

__global__ __launch_bounds__(256) void k_pool(
    const unsigned short* __restrict__ xf,
    const int* __restrict__ batch,
    unsigned short* __restrict__ g)
{
    __shared__ float red[16][HDIM];
    int gid = blockIdx.x;
    int tid = threadIdx.x;

    int lo = 0, hi = N_NODES;
    while (lo < hi) { int mid = (lo + hi) >> 1; if (batch[mid] < gid) lo = mid + 1; else hi = mid; }
    int start = lo;
    int lo2 = start, hi2 = N_NODES;
    while (lo2 < hi2) { int mid = (lo2 + hi2) >> 1; if (batch[mid] < gid + 1) lo2 = mid + 1; else hi2 = mid; }
    int end = lo2;

    int tsub = tid & 15, rgrp = tid >> 4;
    int seg = tsub * 8;
    float acc[8] = {0.f, 0.f, 0.f, 0.f, 0.f, 0.f, 0.f, 0.f};
    for (int r = start + rgrp; r < end; r += 16) {
        short8 v = *(const short8*)(xf + (size_t)r * HDIM + seg);
#pragma unroll
        for (int j = 0; j < 8; ++j) acc[j] += bf2f((unsigned short)v[j]);
    }
#pragma unroll
    for (int j = 0; j < 8; ++j) red[rgrp][seg + j] = acc[j];
    __syncthreads();
    if (tid < HDIM) {
        float s = 0.f;
#pragma unroll
        for (int i = 0; i < 16; ++i) s += red[i][tid];
        g[gid * HDIM + tid] = f2bf(s);
    }
}

// ---------------- head: out = relu(g@hW1+b1) @ hW2 + b2 (block-local) -------
// 8 blocks x 64 rows; stage1 MFMA -> LDS -> stage2 MFMA.

__global__ __launch_bounds__(256) void k_head(
    const unsigned short* __restrict__ g,
    const unsigned short* __restrict__ w1t,  // [128][128] bf16 [n][k]
    const float* __restrict__ b1,
    const unsigned short* __restrict__ w2t,  // [64][128] bf16 [n][k]
    const float* __restrict__ b2,
    float* __restrict__ out)
{
    __shared__ unsigned short tb[64 * HPITCH];
    int tid = threadIdx.x;
    int wv = tid >> 6, lane = tid & 63;
    int m = lane & 15, quad = lane >> 4;
    int row0 = blockIdx.x * 64 + wv * 16;

    short8 a[4];
#pragma unroll
    for (int kk = 0; kk < 4; ++kk)
        a[kk] = *(const short8*)(g + (size_t)(row0 + m) * HDIM + kk * 32 + quad * 8);

    // stage 1: t = relu(g @ W1 + b1), 64x128, staged to LDS
#pragma unroll
    for (int nt = 0; nt < 8; ++nt) {
        floatx4 c = {0.f, 0.f, 0.f, 0.f};
#pragma unroll
        for (int kk = 0; kk < 4; ++kk) {
            short8 b = *(const short8*)(w1t + (nt * 16 + m) * HDIM + kk * 32 + quad * 8);
            c = __builtin_amdgcn_mfma_f32_16x16x32_bf16(a[kk], b, c, 0, 0, 0);
        }
        int n = nt * 16 + m;
        float bias = b1[n];
#pragma unroll
        for (int r = 0; r < 4; ++r) {
            int lrow = wv * 16 + quad * 4 + r;
            tb[lrow * HPITCH + n] = f2bf(fmaxf(c[r] + bias, 0.f));
        }
    }
    __syncthreads();

    // stage 2: out = t @ W2 + b2, 64x64
    short8 a2[4];
#pragma unroll
    for (int kk = 0; kk < 4; ++kk)
        a2[kk] = *(const short8*)&tb[(wv * 16 + m) * HPITCH + kk * 32 + quad * 8];

#pragma unroll
    for (int nt = 0; nt < 4; ++nt) {
        floatx4 c = {0.f, 0.f, 0.f, 0.f};
#pragma unroll
        for (int kk = 0; kk < 4; ++kk) {
            short8 b = *(const short8*)(w2t + (nt * 16 + m) * HDIM + kk * 32 + quad * 8);
            c = __builtin_amdgcn_mfma_f32_16x16x32_bf16(a2[kk], b, c, 0, 0, 0);
        }
        int n = nt * 16 + m;
        float bias = b2[n];
#pragma unroll
        for (int r = 0; r < 4; ++r) {
            int row = row0 + quad * 4 + r;
            out[(size_t)row * ODIM + n] = c[r] + bias;
        }
    }
}

// ---------------- launch ----------------

extern "C" void kernel_launch(void* const* d_in, const int* in_sizes, int n_in,
                              void* d_out, int out_size, void* d_ws, size_t ws_size,
                              hipStream_t stream) {
    const float* x        = (const float*)d_in[0];
    const float* conv_W1  = (const float*)d_in[1];
    const float* conv_b1  = (const float*)d_in[2];
    const float* conv_g   = (const float*)d_in[3];
    const float* conv_be  = (const float*)d_in[4];
    const float* conv_W2  = (const float*)d_in[5];
    const float* conv_b2  = (const float*)d_in[6];
    const float* head_W1  = (const float*)d_in[7];
    const float* head_b1  = (const float*)d_in[8];
    const float* head_W2  = (const float*)d_in[9];
    const float* head_b2  = (const float*)d_in[10];
    const int*   edges    = (const int*)d_in[11];   // [0..E)=src, [E..2E)=dst
    const int*   batch    = (const int*)d_in[12];

    char* ws = (char*)d_ws;
    int*            cnt    = (int*)(ws + 0);                    // 50000*16*4 = 3,200,000 B
    float*          stats  = (float*)(ws + 3200000);            // 3*256*4 = 3,072 B
    int*            colidx = (int*)(ws + 3203072);              // 9,600,000 B
    unsigned short* wtb    = (unsigned short*)(ws + 12803072);  // 122880*2 = 245,760 B
    float*          part   = (float*)(ws + 13048832);           // 256*PBLK*4 = 819,200 B
    unsigned short* gbuf   = (unsigned short*)(ws + 13868032);  // 512*128*2 = 131,072 B
    unsigned short* xa     = (unsigned short*)(ws + 13999104);  // (N+1) rows = 12,800,256 B
    unsigned short* xb     = (unsigned short*)(ws + 26799360);  // 12,800,256 B
    (void)in_sizes; (void)n_in; (void)out_size; (void)ws_size;

    hipMemsetAsync(ws, 0, 3200000, stream);                     // cnt (padded)
    hipMemsetAsync(ws + 13999104 + (size_t)N_NODES * HDIM * 2, 0, HDIM * 2, stream);  // xa sentinel
    hipMemsetAsync(ws + 26799360 + (size_t)N_NODES * HDIM * 2, 0, HDIM * 2, stream);  // xb sentinel

    k_prep<<<SCAT_BLK + CVT_BLK + CVTW_BLK, 256, 0, stream>>>(
        edges, edges + N_EDGES, cnt, colidx, x, xa,
        conv_W1, conv_W2, head_W1, head_W2, wtb);
    k_pad<<<(N_NODES + 255) / 256, 256, 0, stream>>>(cnt, colidx);

    const int gblk = (N_NODES * 16 + 255) / 256;  // 3125
    unsigned short* cur = xa;
    unsigned short* nxt = xb;
    for (int l = 0; l < NLAYER; ++l) {
        // gather: cur -> nxt (y). mlp1: nxt -> cur (h). mlp2: cur -> nxt. swap.
        k_gather<<<gblk, 256, 0, stream>>>(cur, cnt, colidx, nxt);
        k_mlp1<<<NBLK, 256, 0, stream>>>(nxt, wtb + (2 * l) * HDIM * HDIM,
                                         conv_b1 + l * HDIM, cur, part);
        k_stats<<<256, 256, 0, stream>>>(part, stats + l * 256);
        k_mlp2<<<NBLK, 256, 0, stream>>>(cur, stats + l * 256,
                                         conv_g + l * HDIM, conv_be + l * HDIM,
                                         wtb + (2 * l + 1) * HDIM * HDIM,
                                         conv_b2 + l * HDIM, nxt);
        unsigned short* t = cur; cur = nxt; nxt = t;
    }

    k_pool<<<NGRAPH, 256, 0, stream>>>(cur, batch, gbuf);
    k_head<<<NGRAPH / 64, 256, 0, stream>>>(gbuf, wtb + 6 * HDIM * HDIM, head_b1,
                                            wtb + 7 * HDIM * HDIM, head_b2,
                                            (float*)d_out);
}

// Round 7
// 470.599 us; speedup vs baseline: 1.7426x; 1.0123x over previous
//
#include <hip/hip_runtime.h>

#define N_NODES 50000
#define N_EDGES 800000
#define HDIM 128
#define ODIM 64
#define NLAYER 3
#define NGRAPH 512
#define BN_EPS 1e-5f
#define BCAP 48      // bucket capacity; deg ~ Poisson(16), P(deg>=48) ~ 1e-9/node
#define NBLK 782     // mlp grid: ceil(50000/64)
#define PBLK 800     // partial-stats pitch (>= NBLK)
#define HPITCH 136   // LDS pitch for head t-tile
#define TPITCH 136   // LDS pitch for mlp C-tile staging (4-way max conflicts)

// k_prep block-range partition
#define SCAT_BLK 782            // 800000 edges / 4 per thread / 256
#define CVT_BLK 6250            // 1.6M float4
#define CVTW_BLK 481            // 122880 weight elems + 256 sentinel zeros

typedef __attribute__((ext_vector_type(8))) short short8;
typedef __attribute__((ext_vector_type(4))) float floatx4;

static __device__ __forceinline__ unsigned short f2bf(float f) {
    union { float f; unsigned int u; } v; v.f = f;
    unsigned int r = v.u + 0x7FFFu + ((v.u >> 16) & 1u);
    return (unsigned short)(r >> 16);
}
static __device__ __forceinline__ float bf2f(unsigned short s) {
    union { unsigned int u; float f; } v; v.u = ((unsigned int)s) << 16;
    return v.f;
}

// ---- fused prep: scatter (4 edges/thread) + cvt + cvtW + sentinel zero ----

__global__ __launch_bounds__(256) void k_prep(
    const int* __restrict__ src, const int* __restrict__ dst,
    int* __restrict__ cnt, int* __restrict__ colidx,
    const float* __restrict__ x, unsigned short* __restrict__ xb,
    const float* __restrict__ W1, const float* __restrict__ W2,
    const float* __restrict__ hW1, const float* __restrict__ hW2,
    unsigned short* __restrict__ wtb, unsigned short* __restrict__ xa2)
{
    int b = blockIdx.x;
    int tid = threadIdx.x;
    if (b < SCAT_BLK) {
        int base = (b * 256 + tid) * 4;
        if (base < N_EDGES) {
            int4 s4 = *(const int4*)(src + base);
            int4 d4 = *(const int4*)(dst + base);
            int p0 = atomicAdd(&cnt[d4.x], 1);
            int p1 = atomicAdd(&cnt[d4.y], 1);
            int p2 = atomicAdd(&cnt[d4.z], 1);
            int p3 = atomicAdd(&cnt[d4.w], 1);
            if (p0 < BCAP) colidx[d4.x * BCAP + p0] = s4.x;
            if (p1 < BCAP) colidx[d4.y * BCAP + p1] = s4.y;
            if (p2 < BCAP) colidx[d4.z * BCAP + p2] = s4.z;
            if (p3 < BCAP) colidx[d4.w * BCAP + p3] = s4.w;
        }
    } else if (b < SCAT_BLK + CVT_BLK) {
        int i = (b - SCAT_BLK) * 256 + tid;
        if (i < N_NODES * HDIM / 4) {
            float4 v = ((const float4*)x)[i];
            ushort4 o = make_ushort4(f2bf(v.x), f2bf(v.y), f2bf(v.z), f2bf(v.w));
            ((ushort4*)xb)[i] = o;
        }
    } else {
        int idx = (b - SCAT_BLK - CVT_BLK) * 256 + tid;
        if (idx < 6 * HDIM * HDIM) {
            // conv weights: mat 2l=W1[l], 2l+1=W2[l]; [k][n] -> [n][k] bf16
            int mat = idx >> 14;
            int rem = idx & 16383;
            int k = rem >> 7, n = rem & 127;
            int l = mat >> 1;
            const float* W = (mat & 1) ? (W2 + l * HDIM * HDIM) : (W1 + l * HDIM * HDIM);
            wtb[mat * HDIM * HDIM + n * HDIM + k] = f2bf(W[k * HDIM + n]);
        } else if (idx < 7 * HDIM * HDIM) {
            int j = idx - 6 * HDIM * HDIM;
            int n = j >> 7, k = j & 127;
            wtb[idx] = f2bf(hW1[k * HDIM + n]);
        } else if (idx < 7 * HDIM * HDIM + ODIM * HDIM) {
            int j = idx - 7 * HDIM * HDIM;
            int n = j >> 7, k = j & 127;   // n in [0,64)
            wtb[idx] = f2bf(hW2[k * ODIM + n]);
        } else if (idx < 7 * HDIM * HDIM + ODIM * HDIM + HDIM) {
            xb[(size_t)N_NODES * HDIM + (idx - 7 * HDIM * HDIM - ODIM * HDIM)] = 0;
        } else if (idx < 7 * HDIM * HDIM + ODIM * HDIM + 2 * HDIM) {
            xa2[(size_t)N_NODES * HDIM + (idx - 7 * HDIM * HDIM - ODIM * HDIM - HDIM)] = 0;
        }
    }
}

// pad each bucket to a multiple of 8 with sentinel row N_NODES (zero row)
__global__ __launch_bounds__(256) void k_pad(const int* __restrict__ cnt,
                                             int* __restrict__ colidx) {
    int n = blockIdx.x * 256 + threadIdx.x;
    if (n < N_NODES) {
        int d = cnt[n]; if (d > BCAP) d = BCAP;
        int end = (d + 7) & ~7;
        for (int i = d; i < end; ++i) colidx[n * BCAP + i] = N_NODES;
    }
}

// ---------------- gather: y[n] = x[n] + sum_{j in N(n)} x[j] ----------------

__global__ __launch_bounds__(256) void k_gather(
    const unsigned short* __restrict__ x,
    const int* __restrict__ cnt,
    const int* __restrict__ colidx,
    unsigned short* __restrict__ y)
{
    int t = blockIdx.x * 256 + threadIdx.x;
    int node = t >> 4;
    int seg = (t & 15) * 8;          // col offset (8 bf16 = 16 B)
    if (node >= N_NODES) return;

    float acc[8];
    {
        short8 v = *(const short8*)(x + (size_t)node * HDIM + seg);
#pragma unroll
        for (int j = 0; j < 8; ++j) acc[j] = bf2f((unsigned short)v[j]);
    }
    int deg = cnt[node]; if (deg > BCAP) deg = BCAP;
    int e = node * BCAP;
    int end = e + ((deg + 7) & ~7);
#pragma unroll 2
    for (; e < end; e += 8) {
        int4 c0 = *(const int4*)(colidx + e);
        int4 c1 = *(const int4*)(colidx + e + 4);
        short8 v0 = *(const short8*)(x + (size_t)c0.x * HDIM + seg);
        short8 v1 = *(const short8*)(x + (size_t)c0.y * HDIM + seg);
        short8 v2 = *(const short8*)(x + (size_t)c0.z * HDIM + seg);
        short8 v3 = *(const short8*)(x + (size_t)c0.w * HDIM + seg);
        short8 v4 = *(const short8*)(x + (size_t)c1.x * HDIM + seg);
        short8 v5 = *(const short8*)(x + (size_t)c1.y * HDIM + seg);
        short8 v6 = *(const short8*)(x + (size_t)c1.z * HDIM + seg);
        short8 v7 = *(const short8*)(x + (size_t)c1.w * HDIM + seg);
#pragma unroll
        for (int j = 0; j < 8; ++j)
            acc[j] += ((bf2f((unsigned short)v0[j]) + bf2f((unsigned short)v1[j])) +
                       (bf2f((unsigned short)v2[j]) + bf2f((unsigned short)v3[j]))) +
                      ((bf2f((unsigned short)v4[j]) + bf2f((unsigned short)v5[j])) +
                       (bf2f((unsigned short)v6[j]) + bf2f((unsigned short)v7[j])));
    }
    short8 o;
#pragma unroll
    for (int j = 0; j < 8; ++j) o[j] = (short)f2bf(acc[j]);
    *(short8*)(y + (size_t)node * HDIM + seg) = o;
}

// ------- mlp1: h = y @ W1 + b1, partial BN stats; LDS-staged C store -------

__global__ __launch_bounds__(256) void k_mlp1(
    const unsigned short* __restrict__ y,
    const unsigned short* __restrict__ wt,   // [n][k] bf16
    const float* __restrict__ b1,
    unsigned short* __restrict__ hout,
    float* __restrict__ pout)                // [256][PBLK] partials
{
    __shared__ float s_sum[HDIM], s_sq[HDIM];
    __shared__ __align__(16) unsigned short tb[64 * TPITCH];
    int tid = threadIdx.x;
    if (tid < HDIM) { s_sum[tid] = 0.f; s_sq[tid] = 0.f; }
    __syncthreads();

    int wv = tid >> 6, lane = tid & 63;
    int m = lane & 15, quad = lane >> 4;
    int row0 = blockIdx.x * 64 + wv * 16;
    int arow = row0 + m;

    short8 a[4];
    if (arow < N_NODES) {
#pragma unroll
        for (int kk = 0; kk < 4; ++kk)
            a[kk] = *(const short8*)(y + (size_t)arow * HDIM + kk * 32 + quad * 8);
    } else {
#pragma unroll
        for (int kk = 0; kk < 4; ++kk) a[kk] = (short8)0;
    }

    floatx4 acc[8];
#pragma unroll
    for (int nt = 0; nt < 8; ++nt) {
        floatx4 c = {0.f, 0.f, 0.f, 0.f};
#pragma unroll
        for (int kk = 0; kk < 4; ++kk) {
            short8 b = *(const short8*)(wt + (nt * 16 + m) * HDIM + kk * 32 + quad * 8);
            c = __builtin_amdgcn_mfma_f32_16x16x32_bf16(a[kk], b, c, 0, 0, 0);
        }
        acc[nt] = c;
    }

    // stats (guarded) + stage C-tile to LDS
    int lrow0 = wv * 16 + quad * 4;
#pragma unroll
    for (int nt = 0; nt < 8; ++nt) {
        int n = nt * 16 + m;
        float bias = b1[n];
        float ssum = 0.f, ssq = 0.f;
#pragma unroll
        for (int r = 0; r < 4; ++r) {
            float val = acc[nt][r] + bias;
            tb[(lrow0 + r) * TPITCH + n] = f2bf(val);
            if (row0 + quad * 4 + r < N_NODES) { ssum += val; ssq += val * val; }
        }
        atomicAdd(&s_sum[n], ssum);
        atomicAdd(&s_sq[n], ssq);
    }
    __syncthreads();
    if (tid < HDIM) {
        pout[(size_t)tid * PBLK + blockIdx.x] = s_sum[tid];
        pout[(size_t)(tid + HDIM) * PBLK + blockIdx.x] = s_sq[tid];
    }
    // coalesced 16B stores: 4 threads per row
    int lrow = tid >> 2, off = (tid & 3) * 32;
    int grow = blockIdx.x * 64 + lrow;
    if (grow < N_NODES) {
#pragma unroll
        for (int i = 0; i < 4; ++i)
            *(short8*)(hout + (size_t)grow * HDIM + off + i * 8) =
                *(const short8*)&tb[lrow * TPITCH + off + i * 8];
    }
}

// ---------------- stats: reduce partials, one block per column ----------------

__global__ __launch_bounds__(256) void k_stats(const float* __restrict__ p,
                                               float* __restrict__ stats) {
    int c = blockIdx.x;          // 0..255 (128 sum + 128 sumsq)
    int tid = threadIdx.x;
    const float* col = p + (size_t)c * PBLK;
    float s = 0.f;
    for (int i = tid; i < NBLK; i += 256) s += col[i];
#pragma unroll
    for (int off = 32; off; off >>= 1) s += __shfl_down(s, off, 64);
    __shared__ float red[4];
    if ((tid & 63) == 0) red[tid >> 6] = s;
    __syncthreads();
    if (tid == 0) stats[c] = red[0] + red[1] + red[2] + red[3];
}

// ------- mlp2: x' = relu(BN(h) relu'd @ W2 + b2); LDS-staged C store -------

__global__ __launch_bounds__(256) void k_mlp2(
    const unsigned short* __restrict__ hin,
    const float* __restrict__ stats,
    const float* __restrict__ gamma,
    const float* __restrict__ beta,
    const unsigned short* __restrict__ wt,   // [n][k] bf16
    const float* __restrict__ b2,
    unsigned short* __restrict__ xout)
{
    __shared__ float s_scale[HDIM], s_shift[HDIM];
    __shared__ __align__(16) unsigned short tb[64 * TPITCH];
    int tid = threadIdx.x;
    if (tid < HDIM) {
        float mu = stats[tid] * (1.f / N_NODES);
        float var = stats[HDIM + tid] * (1.f / N_NODES) - mu * mu;
        float sc = gamma[tid] * rsqrtf(var + BN_EPS);
        s_scale[tid] = sc;
        s_shift[tid] = beta[tid] - mu * sc;
    }
    __syncthreads();

    int wv = tid >> 6, lane = tid & 63;
    int m = lane & 15, quad = lane >> 4;
    int row0 = blockIdx.x * 64 + wv * 16;
    int arow = row0 + m;

    short8 a[4];
    if (arow < N_NODES) {
#pragma unroll
        for (int kk = 0; kk < 4; ++kk) {
            short8 v = *(const short8*)(hin + (size_t)arow * HDIM + kk * 32 + quad * 8);
            int c0 = kk * 32 + quad * 8;
            short8 af;
#pragma unroll
            for (int j = 0; j < 8; ++j) {
                float f = fmaxf(bf2f((unsigned short)v[j]) * s_scale[c0 + j] + s_shift[c0 + j], 0.f);
                af[j] = (short)f2bf(f);
            }
            a[kk] = af;
        }
    } else {
#pragma unroll
        for (int kk = 0; kk < 4; ++kk) a[kk] = (short8)0;
    }

    floatx4 acc[8];
#pragma unroll
    for (int nt = 0; nt < 8; ++nt) {
        floatx4 c = {0.f, 0.f, 0.f, 0.f};
#pragma unroll
        for (int kk = 0; kk < 4; ++kk) {
            short8 b = *(const short8*)(wt + (nt * 16 + m) * HDIM + kk * 32 + quad * 8);
            c = __builtin_amdgcn_mfma_f32_16x16x32_bf16(a[kk], b, c, 0, 0, 0);
        }
        acc[nt] = c;
    }

    int lrow0 = wv * 16 + quad * 4;
#pragma unroll
    for (int nt = 0; nt < 8; ++nt) {
        int n = nt * 16 + m;
        float bias = b2[n];
#pragma unroll
        for (int r = 0; r < 4; ++r)
            tb[(lrow0 + r) * TPITCH + n] = f2bf(fmaxf(acc[nt][r] + bias, 0.f));
    }
    __syncthreads();
    int lrow = tid >> 2, off = (tid & 3) * 32;
    int grow = blockIdx.x * 64 + lrow;
    if (grow < N_NODES) {
#pragma unroll
        for (int i = 0; i < 4; ++i)
            *(short8*)(xout + (size_t)grow * HDIM + off + i * 8) =
                *(const short8*)&tb[lrow * TPITCH + off + i * 8];
    }
}

// ---------------- pool: g[gid] = sum of node rows (bf16 out) ----------------

__global__ __launch_bounds__(256) void k_pool(
    const unsigned short* __restrict__ xf,
    const int* __restrict__ batch,
    unsigned short* __restrict__ g)
{
    __shared__ float red[16][HDIM];
    int gid = blockIdx.x;
    int tid = threadIdx.x;

    int lo = 0, hi = N_NODES;
    while (lo < hi) { int mid = (lo + hi) >> 1; if (batch[mid] < gid) lo = mid + 1; else hi = mid; }
    int start = lo;
    int lo2 = start, hi2 = N_NODES;
    while (lo2 < hi2) { int mid = (lo2 + hi2) >> 1; if (batch[mid] < gid + 1) lo2 = mid + 1; else hi2 = mid; }
    int end = lo2;

    int tsub = tid & 15, rgrp = tid >> 4;
    int seg = tsub * 8;
    float acc[8] = {0.f, 0.f, 0.f, 0.f, 0.f, 0.f, 0.f, 0.f};
    for (int r = start + rgrp; r < end; r += 16) {
        short8 v = *(const short8*)(xf + (size_t)r * HDIM + seg);
#pragma unroll
        for (int j = 0; j < 8; ++j) acc[j] += bf2f((unsigned short)v[j]);
    }
#pragma unroll
    for (int j = 0; j < 8; ++j) red[rgrp][seg + j] = acc[j];
    __syncthreads();
    if (tid < HDIM) {
        float s = 0.f;
#pragma unroll
        for (int i = 0; i < 16; ++i) s += red[i][tid];
        g[gid * HDIM + tid] = f2bf(s);
    }
}

// ---------------- head: out = relu(g@hW1+b1) @ hW2 + b2 (block-local) -------

__global__ __launch_bounds__(256) void k_head(
    const unsigned short* __restrict__ g,
    const unsigned short* __restrict__ w1t,  // [128][128] bf16 [n][k]
    const float* __restrict__ b1,
    const unsigned short* __restrict__ w2t,  // [64][128] bf16 [n][k]
    const float* __restrict__ b2,
    float* __restrict__ out)
{
    __shared__ unsigned short tb[64 * HPITCH];
    int tid = threadIdx.x;
    int wv = tid >> 6, lane = tid & 63;
    int m = lane & 15, quad = lane >> 4;
    int row0 = blockIdx.x * 64 + wv * 16;

    short8 a[4];
#pragma unroll
    for (int kk = 0; kk < 4; ++kk)
        a[kk] = *(const short8*)(g + (size_t)(row0 + m) * HDIM + kk * 32 + quad * 8);

    // stage 1: t = relu(g @ W1 + b1), 64x128, staged to LDS
#pragma unroll
    for (int nt = 0; nt < 8; ++nt) {
        floatx4 c = {0.f, 0.f, 0.f, 0.f};
#pragma unroll
        for (int kk = 0; kk < 4; ++kk) {
            short8 b = *(const short8*)(w1t + (nt * 16 + m) * HDIM + kk * 32 + quad * 8);
            c = __builtin_amdgcn_mfma_f32_16x16x32_bf16(a[kk], b, c, 0, 0, 0);
        }
        int n = nt * 16 + m;
        float bias = b1[n];
#pragma unroll
        for (int r = 0; r < 4; ++r) {
            int lrow = wv * 16 + quad * 4 + r;
            tb[lrow * HPITCH + n] = f2bf(fmaxf(c[r] + bias, 0.f));
        }
    }
    __syncthreads();

    // stage 2: out = t @ W2 + b2, 64x64
    short8 a2[4];
#pragma unroll
    for (int kk = 0; kk < 4; ++kk)
        a2[kk] = *(const short8*)&tb[(wv * 16 + m) * HPITCH + kk * 32 + quad * 8];

#pragma unroll
    for (int nt = 0; nt < 4; ++nt) {
        floatx4 c = {0.f, 0.f, 0.f, 0.f};
#pragma unroll
        for (int kk = 0; kk < 4; ++kk) {
            short8 b = *(const short8*)(w2t + (nt * 16 + m) * HDIM + kk * 32 + quad * 8);
            c = __builtin_amdgcn_mfma_f32_16x16x32_bf16(a2[kk], b, c, 0, 0, 0);
        }
        int n = nt * 16 + m;
        float bias = b2[n];
#pragma unroll
        for (int r = 0; r < 4; ++r) {
            int row = row0 + quad * 4 + r;
            out[(size_t)row * ODIM + n] = c[r] + bias;
        }
    }
}

// ---------------- launch ----------------

extern "C" void kernel_launch(void* const* d_in, const int* in_sizes, int n_in,
                              void* d_out, int out_size, void* d_ws, size_t ws_size,
                              hipStream_t stream) {
    const float* x        = (const float*)d_in[0];
    const float* conv_W1  = (const float*)d_in[1];
    const float* conv_b1  = (const float*)d_in[2];
    const float* conv_g   = (const float*)d_in[3];
    const float* conv_be  = (const float*)d_in[4];
    const float* conv_W2  = (const float*)d_in[5];
    const float* conv_b2  = (const float*)d_in[6];
    const float* head_W1  = (const float*)d_in[7];
    const float* head_b1  = (const float*)d_in[8];
    const float* head_W2  = (const float*)d_in[9];
    const float* head_b2  = (const float*)d_in[10];
    const int*   edges    = (const int*)d_in[11];   // [0..E)=src, [E..2E)=dst
    const int*   batch    = (const int*)d_in[12];

    char* ws = (char*)d_ws;
    int*            cnt    = (int*)(ws + 0);                    // 200,000 B
    float*          stats  = (float*)(ws + 200000);             // 3*256*4 = 3,072 B
    int*            colidx = (int*)(ws + 203072);               // 9,600,000 B
    unsigned short* wtb    = (unsigned short*)(ws + 9803072);   // 245,760 B
    float*          part   = (float*)(ws + 10048832);           // 819,200 B
    unsigned short* gbuf   = (unsigned short*)(ws + 10868032);  // 131,072 B
    unsigned short* xa     = (unsigned short*)(ws + 10999104);  // (N+1) rows = 12,800,256 B
    unsigned short* xb     = (unsigned short*)(ws + 23799360);  // 12,800,256 B
    (void)in_sizes; (void)n_in; (void)out_size; (void)ws_size;

    hipMemsetAsync(ws, 0, 200000, stream);                      // cnt only

    k_prep<<<SCAT_BLK + CVT_BLK + CVTW_BLK, 256, 0, stream>>>(
        edges, edges + N_EDGES, cnt, colidx, x, xa,
        conv_W1, conv_W2, head_W1, head_W2, wtb, xb);
    k_pad<<<(N_NODES + 255) / 256, 256, 0, stream>>>(cnt, colidx);

    const int gblk = (N_NODES * 16 + 255) / 256;  // 3125
    unsigned short* cur = xa;
    unsigned short* nxt = xb;
    for (int l = 0; l < NLAYER; ++l) {
        // gather: cur -> nxt (y). mlp1: nxt -> cur (h). mlp2: cur -> nxt. swap.
        k_gather<<<gblk, 256, 0, stream>>>(cur, cnt, colidx, nxt);
        k_mlp1<<<NBLK, 256, 0, stream>>>(nxt, wtb + (2 * l) * HDIM * HDIM,
                                         conv_b1 + l * HDIM, cur, part);
        k_stats<<<256, 256, 0, stream>>>(part, stats + l * 256);
        k_mlp2<<<NBLK, 256, 0, stream>>>(cur, stats + l * 256,
                                         conv_g + l * HDIM, conv_be + l * HDIM,
                                         wtb + (2 * l + 1) * HDIM * HDIM,
                                         conv_b2 + l * HDIM, nxt);
        unsigned short* t = cur; cur = nxt; nxt = t;
    }

    k_pool<<<NGRAPH, 256, 0, stream>>>(cur, batch, gbuf);
    k_head<<<NGRAPH / 64, 256, 0, stream>>>(gbuf, wtb + 6 * HDIM * HDIM, head_b1,
                                            wtb + 7 * HDIM * HDIM, head_b2,
                                            (float*)d_out);
}

// Round 8
// 438.992 us; speedup vs baseline: 1.8681x; 1.0720x over previous
//
#include <hip/hip_runtime.h>

#define N_NODES 50000
#define N_EDGES 800000
#define HDIM 128
#define ODIM 64
#define NLAYER 3
#define NGRAPH 512
#define BN_EPS 1e-5f
#define BCAP 48      // bucket capacity; deg ~ Poisson(16), P(deg>=48) ~ 1e-9/node
#define NBLK 782     // ceil(50000/64)
#define PBLK 800     // partial-stats pitch (>= NBLK)
#define HPITCH 136   // LDS pitch for head t-tile
#define TPITCH 136   // LDS pitch for y/C tiles

// k_prep block-range partition
#define SCAT_BLK 782            // 800000 edges / 4 per thread / 256
#define CVT_BLK 6250            // 1.6M float4
#define CVTW_BLK 481            // 122880 weight elems + 256 sentinel zeros

typedef __attribute__((ext_vector_type(8))) short short8;
typedef __attribute__((ext_vector_type(4))) float floatx4;

static __device__ __forceinline__ unsigned short f2bf(float f) {
    union { float f; unsigned int u; } v; v.f = f;
    unsigned int r = v.u + 0x7FFFu + ((v.u >> 16) & 1u);
    return (unsigned short)(r >> 16);
}
static __device__ __forceinline__ float bf2f(unsigned short s) {
    union { unsigned int u; float f; } v; v.u = ((unsigned int)s) << 16;
    return v.f;
}

// ---- fused prep: scatter (4 edges/thread) + cvt + cvtW + sentinel zero ----

__global__ __launch_bounds__(256) void k_prep(
    const int* __restrict__ src, const int* __restrict__ dst,
    int* __restrict__ cnt, int* __restrict__ colidx,
    const float* __restrict__ x, unsigned short* __restrict__ xb,
    const float* __restrict__ W1, const float* __restrict__ W2,
    const float* __restrict__ hW1, const float* __restrict__ hW2,
    unsigned short* __restrict__ wtb, unsigned short* __restrict__ xa2)
{
    int b = blockIdx.x;
    int tid = threadIdx.x;
    if (b < SCAT_BLK) {
        int base = (b * 256 + tid) * 4;
        if (base < N_EDGES) {
            int4 s4 = *(const int4*)(src + base);
            int4 d4 = *(const int4*)(dst + base);
            int p0 = atomicAdd(&cnt[d4.x], 1);
            int p1 = atomicAdd(&cnt[d4.y], 1);
            int p2 = atomicAdd(&cnt[d4.z], 1);
            int p3 = atomicAdd(&cnt[d4.w], 1);
            if (p0 < BCAP) colidx[d4.x * BCAP + p0] = s4.x;
            if (p1 < BCAP) colidx[d4.y * BCAP + p1] = s4.y;
            if (p2 < BCAP) colidx[d4.z * BCAP + p2] = s4.z;
            if (p3 < BCAP) colidx[d4.w * BCAP + p3] = s4.w;
        }
    } else if (b < SCAT_BLK + CVT_BLK) {
        int i = (b - SCAT_BLK) * 256 + tid;
        if (i < N_NODES * HDIM / 4) {
            float4 v = ((const float4*)x)[i];
            ushort4 o = make_ushort4(f2bf(v.x), f2bf(v.y), f2bf(v.z), f2bf(v.w));
            ((ushort4*)xb)[i] = o;
        }
    } else {
        int idx = (b - SCAT_BLK - CVT_BLK) * 256 + tid;
        if (idx < 6 * HDIM * HDIM) {
            // conv weights: mat 2l=W1[l], 2l+1=W2[l]; [k][n] -> [n][k] bf16
            int mat = idx >> 14;
            int rem = idx & 16383;
            int k = rem >> 7, n = rem & 127;
            int l = mat >> 1;
            const float* W = (mat & 1) ? (W2 + l * HDIM * HDIM) : (W1 + l * HDIM * HDIM);
            wtb[mat * HDIM * HDIM + n * HDIM + k] = f2bf(W[k * HDIM + n]);
        } else if (idx < 7 * HDIM * HDIM) {
            int j = idx - 6 * HDIM * HDIM;
            int n = j >> 7, k = j & 127;
            wtb[idx] = f2bf(hW1[k * HDIM + n]);
        } else if (idx < 7 * HDIM * HDIM + ODIM * HDIM) {
            int j = idx - 7 * HDIM * HDIM;
            int n = j >> 7, k = j & 127;   // n in [0,64)
            wtb[idx] = f2bf(hW2[k * ODIM + n]);
        } else if (idx < 7 * HDIM * HDIM + ODIM * HDIM + HDIM) {
            xb[(size_t)N_NODES * HDIM + (idx - 7 * HDIM * HDIM - ODIM * HDIM)] = 0;
        } else if (idx < 7 * HDIM * HDIM + ODIM * HDIM + 2 * HDIM) {
            xa2[(size_t)N_NODES * HDIM + (idx - 7 * HDIM * HDIM - ODIM * HDIM - HDIM)] = 0;
        }
    }
}

// pad each bucket to a multiple of 8 with sentinel row N_NODES (zero row)
__global__ __launch_bounds__(256) void k_pad(const int* __restrict__ cnt,
                                             int* __restrict__ colidx) {
    int n = blockIdx.x * 256 + threadIdx.x;
    if (n < N_NODES) {
        int d = cnt[n]; if (d > BCAP) d = BCAP;
        int end = (d + 7) & ~7;
        for (int i = d; i < end; ++i) colidx[n * BCAP + i] = N_NODES;
    }
}

// ---- fused gather + mlp1: y=x+sum(neigh) in LDS, h=y@W1+b1, BN partials ----
// 512 threads, 64 nodes/block. Phase1: 1024 gather tasks (node,16B-seg), 2/thread.
// Phase2: 8 waves, wave w -> rows (w&3)*16.., cols (w>>2)*64..; LDS tile reused for C.

__global__ __launch_bounds__(512, 6) void k_gml(
    const unsigned short* __restrict__ x,
    const int* __restrict__ cnt,
    const int* __restrict__ colidx,
    const unsigned short* __restrict__ wt,   // [n][k] bf16
    const float* __restrict__ b1,
    unsigned short* __restrict__ hout,
    float* __restrict__ pout)                // [256][PBLK] partials
{
    __shared__ float s_sum[HDIM], s_sq[HDIM];
    __shared__ __align__(16) unsigned short yb[64 * TPITCH];
    int tid = threadIdx.x;
    if (tid < HDIM) { s_sum[tid] = 0.f; s_sq[tid] = 0.f; }
    int nbase = blockIdx.x * 64;

    // ---- gather into LDS ----
#pragma unroll
    for (int t = tid; t < 1024; t += 512) {
        int nl = t >> 4;
        int seg = (t & 15) * 8;
        int gnode = nbase + nl;
        float acc[8] = {0.f, 0.f, 0.f, 0.f, 0.f, 0.f, 0.f, 0.f};
        if (gnode < N_NODES) {
            short8 v = *(const short8*)(x + (size_t)gnode * HDIM + seg);
#pragma unroll
            for (int j = 0; j < 8; ++j) acc[j] = bf2f((unsigned short)v[j]);
            int deg = cnt[gnode]; if (deg > BCAP) deg = BCAP;
            int e = gnode * BCAP;
            int end = e + ((deg + 7) & ~7);
            for (; e < end; e += 8) {
                int4 c0 = *(const int4*)(colidx + e);
                int4 c1 = *(const int4*)(colidx + e + 4);
                short8 v0 = *(const short8*)(x + (size_t)c0.x * HDIM + seg);
                short8 v1 = *(const short8*)(x + (size_t)c0.y * HDIM + seg);
                short8 v2 = *(const short8*)(x + (size_t)c0.z * HDIM + seg);
                short8 v3 = *(const short8*)(x + (size_t)c0.w * HDIM + seg);
                short8 v4 = *(const short8*)(x + (size_t)c1.x * HDIM + seg);
                short8 v5 = *(const short8*)(x + (size_t)c1.y * HDIM + seg);
                short8 v6 = *(const short8*)(x + (size_t)c1.z * HDIM + seg);
                short8 v7 = *(const short8*)(x + (size_t)c1.w * HDIM + seg);
#pragma unroll
                for (int j = 0; j < 8; ++j)
                    acc[j] += ((bf2f((unsigned short)v0[j]) + bf2f((unsigned short)v1[j])) +
                               (bf2f((unsigned short)v2[j]) + bf2f((unsigned short)v3[j]))) +
                              ((bf2f((unsigned short)v4[j]) + bf2f((unsigned short)v5[j])) +
                               (bf2f((unsigned short)v6[j]) + bf2f((unsigned short)v7[j])));
            }
        }
        short8 o;
#pragma unroll
        for (int j = 0; j < 8; ++j) o[j] = (short)f2bf(acc[j]);
        *(short8*)&yb[nl * TPITCH + seg] = o;
    }
    __syncthreads();

    // ---- MFMA: h = y @ W1 ----
    int wv = tid >> 6, lane = tid & 63;
    int m = lane & 15, quad = lane >> 4;
    int mrow = (wv & 3) * 16 + m;
    int ncol0 = (wv >> 2) * 64;

    short8 a[4];
#pragma unroll
    for (int kk = 0; kk < 4; ++kk)
        a[kk] = *(const short8*)&yb[mrow * TPITCH + kk * 32 + quad * 8];
    __syncthreads();   // all A-frag reads complete before C overwrites yb

    floatx4 acc4[4];
#pragma unroll
    for (int nt = 0; nt < 4; ++nt) {
        floatx4 c = {0.f, 0.f, 0.f, 0.f};
#pragma unroll
        for (int kk = 0; kk < 4; ++kk) {
            short8 b = *(const short8*)(wt + (ncol0 + nt * 16 + m) * HDIM + kk * 32 + quad * 8);
            c = __builtin_amdgcn_mfma_f32_16x16x32_bf16(a[kk], b, c, 0, 0, 0);
        }
        acc4[nt] = c;
    }

    // epilogue: +b1, stats, C -> LDS
    int lrow0 = (wv & 3) * 16 + quad * 4;
#pragma unroll
    for (int nt = 0; nt < 4; ++nt) {
        int n = ncol0 + nt * 16 + m;
        float bias = b1[n];
        float ssum = 0.f, ssq = 0.f;
#pragma unroll
        for (int r = 0; r < 4; ++r) {
            float val = acc4[nt][r] + bias;
            yb[(lrow0 + r) * TPITCH + n] = f2bf(val);
            if (nbase + lrow0 + r < N_NODES) { ssum += val; ssq += val * val; }
        }
        atomicAdd(&s_sum[n], ssum);
        atomicAdd(&s_sq[n], ssq);
    }
    __syncthreads();
    if (tid < HDIM) {
        pout[(size_t)tid * PBLK + blockIdx.x] = s_sum[tid];
        pout[(size_t)(tid + HDIM) * PBLK + blockIdx.x] = s_sq[tid];
    }
    // coalesced store: 8 threads/row, 32 B each
    int lrow = tid >> 3, off = (tid & 7) * 16;
    int grow = nbase + lrow;
    if (grow < N_NODES) {
        *(short8*)(hout + (size_t)grow * HDIM + off) = *(const short8*)&yb[lrow * TPITCH + off];
        *(short8*)(hout + (size_t)grow * HDIM + off + 8) = *(const short8*)&yb[lrow * TPITCH + off + 8];
    }
}

// ---------------- stats: reduce partials, one block per column ----------------

__global__ __launch_bounds__(256) void k_stats(const float* __restrict__ p,
                                               float* __restrict__ stats) {
    int c = blockIdx.x;          // 0..255 (128 sum + 128 sumsq)
    int tid = threadIdx.x;
    const float* col = p + (size_t)c * PBLK;
    float s = 0.f;
    for (int i = tid; i < NBLK; i += 256) s += col[i];
#pragma unroll
    for (int off = 32; off; off >>= 1) s += __shfl_down(s, off, 64);
    __shared__ float red[4];
    if ((tid & 63) == 0) red[tid >> 6] = s;
    __syncthreads();
    if (tid == 0) stats[c] = red[0] + red[1] + red[2] + red[3];
}

// ------- mlp2: x' = relu(BN(h) relu'd @ W2 + b2); LDS-staged C store -------

__global__ __launch_bounds__(256) void k_mlp2(
    const unsigned short* __restrict__ hin,
    const float* __restrict__ stats,
    const float* __restrict__ gamma,
    const float* __restrict__ beta,
    const unsigned short* __restrict__ wt,   // [n][k] bf16
    const float* __restrict__ b2,
    unsigned short* __restrict__ xout)
{
    __shared__ float s_scale[HDIM], s_shift[HDIM];
    __shared__ __align__(16) unsigned short tb[64 * TPITCH];
    int tid = threadIdx.x;
    if (tid < HDIM) {
        float mu = stats[tid] * (1.f / N_NODES);
        float var = stats[HDIM + tid] * (1.f / N_NODES) - mu * mu;
        float sc = gamma[tid] * rsqrtf(var + BN_EPS);
        s_scale[tid] = sc;
        s_shift[tid] = beta[tid] - mu * sc;
    }
    __syncthreads();

    int wv = tid >> 6, lane = tid & 63;
    int m = lane & 15, quad = lane >> 4;
    int row0 = blockIdx.x * 64 + wv * 16;
    int arow = row0 + m;

    short8 a[4];
    if (arow < N_NODES) {
#pragma unroll
        for (int kk = 0; kk < 4; ++kk) {
            short8 v = *(const short8*)(hin + (size_t)arow * HDIM + kk * 32 + quad * 8);
            int c0 = kk * 32 + quad * 8;
            short8 af;
#pragma unroll
            for (int j = 0; j < 8; ++j) {
                float f = fmaxf(bf2f((unsigned short)v[j]) * s_scale[c0 + j] + s_shift[c0 + j], 0.f);
                af[j] = (short)f2bf(f);
            }
            a[kk] = af;
        }
    } else {
#pragma unroll
        for (int kk = 0; kk < 4; ++kk) a[kk] = (short8)0;
    }

    floatx4 acc[8];
#pragma unroll
    for (int nt = 0; nt < 8; ++nt) {
        floatx4 c = {0.f, 0.f, 0.f, 0.f};
#pragma unroll
        for (int kk = 0; kk < 4; ++kk) {
            short8 b = *(const short8*)(wt + (nt * 16 + m) * HDIM + kk * 32 + quad * 8);
            c = __builtin_amdgcn_mfma_f32_16x16x32_bf16(a[kk], b, c, 0, 0, 0);
        }
        acc[nt] = c;
    }

    int lrow0 = wv * 16 + quad * 4;
#pragma unroll
    for (int nt = 0; nt < 8; ++nt) {
        int n = nt * 16 + m;
        float bias = b2[n];
#pragma unroll
        for (int r = 0; r < 4; ++r)
            tb[(lrow0 + r) * TPITCH + n] = f2bf(fmaxf(acc[nt][r] + bias, 0.f));
    }
    __syncthreads();
    int lrow = tid >> 2, off = (tid & 3) * 32;
    int grow = blockIdx.x * 64 + lrow;
    if (grow < N_NODES) {
#pragma unroll
        for (int i = 0; i < 4; ++i)
            *(short8*)(xout + (size_t)grow * HDIM + off + i * 8) =
                *(const short8*)&tb[lrow * TPITCH + off + i * 8];
    }
}

// ---------------- pool: g[gid] = sum of node rows (bf16 out) ----------------

__global__ __launch_bounds__(256) void k_pool(
    const unsigned short* __restrict__ xf,
    const int* __restrict__ batch,
    unsigned short* __restrict__ g)
{
    __shared__ float red[16][HDIM];
    int gid = blockIdx.x;
    int tid = threadIdx.x;

    int lo = 0, hi = N_NODES;
    while (lo < hi) { int mid = (lo + hi) >> 1; if (batch[mid] < gid) lo = mid + 1; else hi = mid; }
    int start = lo;
    int lo2 = start, hi2 = N_NODES;
    while (lo2 < hi2) { int mid = (lo2 + hi2) >> 1; if (batch[mid] < gid + 1) lo2 = mid + 1; else hi2 = mid; }
    int end = lo2;

    int tsub = tid & 15, rgrp = tid >> 4;
    int seg = tsub * 8;
    float acc[8] = {0.f, 0.f, 0.f, 0.f, 0.f, 0.f, 0.f, 0.f};
    for (int r = start + rgrp; r < end; r += 16) {
        short8 v = *(const short8*)(xf + (size_t)r * HDIM + seg);
#pragma unroll
        for (int j = 0; j < 8; ++j) acc[j] += bf2f((unsigned short)v[j]);
    }
#pragma unroll
    for (int j = 0; j < 8; ++j) red[rgrp][seg + j] = acc[j];
    __syncthreads();
    if (tid < HDIM) {
        float s = 0.f;
#pragma unroll
        for (int i = 0; i < 16; ++i) s += red[i][tid];
        g[gid * HDIM + tid] = f2bf(s);
    }
}

// ---------------- head: out = relu(g@hW1+b1) @ hW2 + b2 (block-local) -------

__global__ __launch_bounds__(256) void k_head(
    const unsigned short* __restrict__ g,
    const unsigned short* __restrict__ w1t,  // [128][128] bf16 [n][k]
    const float* __restrict__ b1,
    const unsigned short* __restrict__ w2t,  // [64][128] bf16 [n][k]
    const float* __restrict__ b2,
    float* __restrict__ out)
{
    __shared__ unsigned short tb[64 * HPITCH];
    int tid = threadIdx.x;
    int wv = tid >> 6, lane = tid & 63;
    int m = lane & 15, quad = lane >> 4;
    int row0 = blockIdx.x * 64 + wv * 16;

    short8 a[4];
#pragma unroll
    for (int kk = 0; kk < 4; ++kk)
        a[kk] = *(const short8*)(g + (size_t)(row0 + m) * HDIM + kk * 32 + quad * 8);

    // stage 1: t = relu(g @ W1 + b1), 64x128, staged to LDS
#pragma unroll
    for (int nt = 0; nt < 8; ++nt) {
        floatx4 c = {0.f, 0.f, 0.f, 0.f};
#pragma unroll
        for (int kk = 0; kk < 4; ++kk) {
            short8 b = *(const short8*)(w1t + (nt * 16 + m) * HDIM + kk * 32 + quad * 8);
            c = __builtin_amdgcn_mfma_f32_16x16x32_bf16(a[kk], b, c, 0, 0, 0);
        }
        int n = nt * 16 + m;
        float bias = b1[n];
#pragma unroll
        for (int r = 0; r < 4; ++r) {
            int lrow = wv * 16 + quad * 4 + r;
            tb[lrow * HPITCH + n] = f2bf(fmaxf(c[r] + bias, 0.f));
        }
    }
    __syncthreads();

    // stage 2: out = t @ W2 + b2, 64x64
    short8 a2[4];
#pragma unroll
    for (int kk = 0; kk < 4; ++kk)
        a2[kk] = *(const short8*)&tb[(wv * 16 + m) * HPITCH + kk * 32 + quad * 8];

#pragma unroll
    for (int nt = 0; nt < 4; ++nt) {
        floatx4 c = {0.f, 0.f, 0.f, 0.f};
#pragma unroll
        for (int kk = 0; kk < 4; ++kk) {
            short8 b = *(const short8*)(w2t + (nt * 16 + m) * HDIM + kk * 32 + quad * 8);
            c = __builtin_amdgcn_mfma_f32_16x16x32_bf16(a2[kk], b, c, 0, 0, 0);
        }
        int n = nt * 16 + m;
        float bias = b2[n];
#pragma unroll
        for (int r = 0; r < 4; ++r) {
            int row = row0 + quad * 4 + r;
            out[(size_t)row * ODIM + n] = c[r] + bias;
        }
    }
}

// ---------------- launch ----------------

extern "C" void kernel_launch(void* const* d_in, const int* in_sizes, int n_in,
                              void* d_out, int out_size, void* d_ws, size_t ws_size,
                              hipStream_t stream) {
    const float* x        = (const float*)d_in[0];
    const float* conv_W1  = (const float*)d_in[1];
    const float* conv_b1  = (const float*)d_in[2];
    const float* conv_g   = (const float*)d_in[3];
    const float* conv_be  = (const float*)d_in[4];
    const float* conv_W2  = (const float*)d_in[5];
    const float* conv_b2  = (const float*)d_in[6];
    const float* head_W1  = (const float*)d_in[7];
    const float* head_b1  = (const float*)d_in[8];
    const float* head_W2  = (const float*)d_in[9];
    const float* head_b2  = (const float*)d_in[10];
    const int*   edges    = (const int*)d_in[11];   // [0..E)=src, [E..2E)=dst
    const int*   batch    = (const int*)d_in[12];

    char* ws = (char*)d_ws;
    int*            cnt    = (int*)(ws + 0);                    // 200,000 B
    float*          stats  = (float*)(ws + 200000);             // 3*256*4 = 3,072 B
    int*            colidx = (int*)(ws + 203072);               // 9,600,000 B
    unsigned short* wtb    = (unsigned short*)(ws + 9803072);   // 245,760 B
    float*          part   = (float*)(ws + 10048832);           // 819,200 B
    unsigned short* gbuf   = (unsigned short*)(ws + 10868032);  // 131,072 B
    unsigned short* xa     = (unsigned short*)(ws + 10999104);  // (N+1) rows = 12,800,256 B
    unsigned short* xb     = (unsigned short*)(ws + 23799360);  // 12,800,256 B
    (void)in_sizes; (void)n_in; (void)out_size; (void)ws_size;

    hipMemsetAsync(ws, 0, 200000, stream);                      // cnt only

    k_prep<<<SCAT_BLK + CVT_BLK + CVTW_BLK, 256, 0, stream>>>(
        edges, edges + N_EDGES, cnt, colidx, x, xa,
        conv_W1, conv_W2, head_W1, head_W2, wtb, xb);
    k_pad<<<(N_NODES + 255) / 256, 256, 0, stream>>>(cnt, colidx);

    // x lives in xa for every layer; h in xb.
    for (int l = 0; l < NLAYER; ++l) {
        k_gml<<<NBLK, 512, 0, stream>>>(xa, cnt, colidx,
                                        wtb + (2 * l) * HDIM * HDIM,
                                        conv_b1 + l * HDIM, xb, part);
        k_stats<<<256, 256, 0, stream>>>(part, stats + l * 256);
        k_mlp2<<<NBLK, 256, 0, stream>>>(xb, stats + l * 256,
                                         conv_g + l * HDIM, conv_be + l * HDIM,
                                         wtb + (2 * l + 1) * HDIM * HDIM,
                                         conv_b2 + l * HDIM, xa);
    }

    k_pool<<<NGRAPH, 256, 0, stream>>>(xa, batch, gbuf);
    k_head<<<NGRAPH / 64, 256, 0, stream>>>(gbuf, wtb + 6 * HDIM * HDIM, head_b1,
                                            wtb + 7 * HDIM * HDIM, head_b2,
                                            (float*)d_out);
}